// Round 1
// baseline (1182.134 us; speedup 1.0000x reference)
//
#include <hip/hip_runtime.h>
#include <math.h>

#define HEADS 4
#define HID 64
#define HC 256
#define NEG_SLOPE 0.2f
#define GG 128

// ---------------- CSR build (counting sort by dst) ----------------
__global__ void fill_counts_kernel(int* counts, int n) {
  int i = blockIdx.x * 256 + threadIdx.x;
  if (i < n) counts[i] = 1;  // every node has one self loop
}

__global__ void hist_kernel(const int* __restrict__ ei, int* counts, int E) {
  int e = blockIdx.x * 256 + threadIdx.x;
  if (e < E) atomicAdd(&counts[ei[E + e]], 1);
}

__global__ void scan_kernel(const int* __restrict__ counts, int* row_ptr, int* cursor, int n) {
  __shared__ int s_sums[256];
  int t = threadIdx.x;
  int chunk = (n + 255) / 256;
  int lo = t * chunk;
  int hi = lo + chunk;
  if (lo > n) lo = n;
  if (hi > n) hi = n;
  int s = 0;
  for (int i = lo; i < hi; ++i) s += counts[i];
  s_sums[t] = s;
  __syncthreads();
  for (int off = 1; off < 256; off <<= 1) {
    int v = (t >= off) ? s_sums[t - off] : 0;
    __syncthreads();
    s_sums[t] += v;
    __syncthreads();
  }
  int run = (t == 0) ? 0 : s_sums[t - 1];
  for (int i = lo; i < hi; ++i) {
    row_ptr[i] = run;
    cursor[i] = run;
    run += counts[i];
  }
  if (t == 255) row_ptr[n] = run;
}

__global__ void scatter_kernel(const int* __restrict__ ei, int* cursor, int* srcs, int E, int n) {
  int i = blockIdx.x * 256 + threadIdx.x;
  if (i >= E + n) return;
  int s, d;
  if (i < E) { s = ei[i]; d = ei[E + i]; }
  else       { s = i - E; d = s; }
  int pos = atomicAdd(&cursor[d], 1);
  srcs[pos] = s;
}

// ---------------- fp32 GEMM: C[M,256] = A[M,256] @ B[256,256] ----------------
#define BM 128
#define BN 128
#define BK 8
__global__ __launch_bounds__(256) void gemm_kernel(const float* __restrict__ A,
                                                   const float* __restrict__ B,
                                                   float* __restrict__ C, int M) {
  __shared__ float As[BK][BM + 4];
  __shared__ float Bs[BK][BN + 4];
  int tid = threadIdx.x;
  int tx = tid & 15, ty = tid >> 4;
  int r0 = blockIdx.y * BM;
  int c0 = blockIdx.x * BN;

  float acc[8][8];
#pragma unroll
  for (int i = 0; i < 8; ++i)
#pragma unroll
    for (int j = 0; j < 8; ++j) acc[i][j] = 0.0f;

  int a_row = tid >> 1;        // 0..127
  int a_c4 = (tid & 1) * 4;    // 0 or 4
  int b_k = tid >> 5;          // 0..7
  int b_c = (tid & 31) * 4;    // 0..124

  for (int k0 = 0; k0 < 256; k0 += BK) {
    float4 av = make_float4(0.f, 0.f, 0.f, 0.f);
    int gr = r0 + a_row;
    if (gr < M) av = *(const float4*)&A[(size_t)gr * 256 + k0 + a_c4];
    As[a_c4 + 0][a_row] = av.x;
    As[a_c4 + 1][a_row] = av.y;
    As[a_c4 + 2][a_row] = av.z;
    As[a_c4 + 3][a_row] = av.w;
    float4 bv = *(const float4*)&B[(size_t)(k0 + b_k) * 256 + c0 + b_c];
    *(float4*)&Bs[b_k][b_c] = bv;
    __syncthreads();
#pragma unroll
    for (int k = 0; k < BK; ++k) {
      float ar[8], br[8];
      float4 a0 = *(float4*)&As[k][ty * 8];
      float4 a1 = *(float4*)&As[k][ty * 8 + 4];
      float4 b0 = *(float4*)&Bs[k][tx * 8];
      float4 b1 = *(float4*)&Bs[k][tx * 8 + 4];
      ar[0] = a0.x; ar[1] = a0.y; ar[2] = a0.z; ar[3] = a0.w;
      ar[4] = a1.x; ar[5] = a1.y; ar[6] = a1.z; ar[7] = a1.w;
      br[0] = b0.x; br[1] = b0.y; br[2] = b0.z; br[3] = b0.w;
      br[4] = b1.x; br[5] = b1.y; br[6] = b1.z; br[7] = b1.w;
#pragma unroll
      for (int i = 0; i < 8; ++i)
#pragma unroll
        for (int j = 0; j < 8; ++j) acc[i][j] += ar[i] * br[j];
    }
    __syncthreads();
  }

#pragma unroll
  for (int i = 0; i < 8; ++i) {
    int gr = r0 + ty * 8 + i;
    if (gr < M) {
      float4 v0 = make_float4(acc[i][0], acc[i][1], acc[i][2], acc[i][3]);
      float4 v1 = make_float4(acc[i][4], acc[i][5], acc[i][6], acc[i][7]);
      *(float4*)&C[(size_t)gr * 256 + c0 + tx * 8] = v0;
      *(float4*)&C[(size_t)gr * 256 + c0 + tx * 8 + 4] = v1;
    }
  }
}

// ---------------- per-node attention scalars ----------------
__global__ void att_kernel(const float* __restrict__ h, const float* __restrict__ att_src,
                           const float* __restrict__ att_dst, float* __restrict__ asrc,
                           float* __restrict__ adst) {
  int n = blockIdx.x, t = threadIdx.x;
  float v = h[(size_t)n * HC + t];
  float ps = v * att_src[t];
  float pd = v * att_dst[t];
  for (int o = 32; o >= 1; o >>= 1) {
    ps += __shfl_xor(ps, o, 64);
    pd += __shfl_xor(pd, o, 64);
  }
  if ((t & 63) == 0) {
    int head = t >> 6;
    asrc[n * HEADS + head] = ps;
    adst[n * HEADS + head] = pd;
  }
}

__device__ __forceinline__ float lrelu(float x) { return x > 0.f ? x : NEG_SLOPE * x; }

// ---------------- segment softmax + weighted aggregation (one block per dst) ----------------
__global__ void aggregate_kernel(const float* __restrict__ hproj, const float* __restrict__ asrc,
                                 const float* __restrict__ adst, const int* __restrict__ row_ptr,
                                 const int* __restrict__ srcs, const float* __restrict__ bias,
                                 float* __restrict__ hout) {
  int node = blockIdx.x;
  int t = threadIdx.x;
  int begin = row_ptr[node], end = row_ptr[node + 1];

  __shared__ float s_red[4][HEADS];
  __shared__ float s_m[HEADS], s_d[HEADS];

  float ad[HEADS];
#pragma unroll
  for (int h = 0; h < HEADS; ++h) ad[h] = adst[node * HEADS + h];

  // pass 1: per-head max of leaky_relu(a_src[s] + a_dst[n])
  float mx[HEADS];
#pragma unroll
  for (int h = 0; h < HEADS; ++h) mx[h] = -3.402823466e38f;
  for (int i = begin + t; i < end; i += 256) {
    int s = srcs[i];
#pragma unroll
    for (int h = 0; h < HEADS; ++h) {
      float e = lrelu(asrc[s * HEADS + h] + ad[h]);
      mx[h] = fmaxf(mx[h], e);
    }
  }
#pragma unroll
  for (int h = 0; h < HEADS; ++h)
    for (int o = 32; o >= 1; o >>= 1) mx[h] = fmaxf(mx[h], __shfl_xor(mx[h], o, 64));
  int wave = t >> 6, lane = t & 63;
  if (lane == 0)
#pragma unroll
    for (int h = 0; h < HEADS; ++h) s_red[wave][h] = mx[h];
  __syncthreads();
  if (t < HEADS) {
    float m = fmaxf(fmaxf(s_red[0][t], s_red[1][t]), fmaxf(s_red[2][t], s_red[3][t]));
    s_m[t] = m;
  }
  __syncthreads();

  // pass 2: per-head sum of exp(e - m)
  float dn[HEADS];
#pragma unroll
  for (int h = 0; h < HEADS; ++h) dn[h] = 0.f;
  for (int i = begin + t; i < end; i += 256) {
    int s = srcs[i];
#pragma unroll
    for (int h = 0; h < HEADS; ++h) {
      float e = lrelu(asrc[s * HEADS + h] + ad[h]);
      dn[h] += __expf(e - s_m[h]);
    }
  }
#pragma unroll
  for (int h = 0; h < HEADS; ++h)
    for (int o = 32; o >= 1; o >>= 1) dn[h] += __shfl_xor(dn[h], o, 64);
  __syncthreads();  // make sure pass-1 reads of s_red are done
  if (lane == 0)
#pragma unroll
    for (int h = 0; h < HEADS; ++h) s_red[wave][h] = dn[h];
  __syncthreads();
  if (t < HEADS) {
    s_d[t] = s_red[0][t] + s_red[1][t] + s_red[2][t] + s_red[3][t];
  }
  __syncthreads();

  // pass 3: weighted accumulation, thread t owns channel t
  int head = t >> 6;
  float m = s_m[head];
  float rd = 1.0f / (s_d[head] + 1e-16f);
  float acc = 0.f;
  for (int i = begin; i < end; ++i) {
    int s = srcs[i];
    float e = lrelu(asrc[s * HEADS + head] + ad[head]);
    float alpha = __expf(e - m) * rd;
    acc += hproj[(size_t)s * HC + t] * alpha;
  }
  float v = acc + bias[t];
  hout[(size_t)node * HC + t] = fmaxf(v, 0.f);
}

// ---------------- global mean pool (batch is sorted) ----------------
__device__ __forceinline__ int lower_bound_i(const int* a, int n, int key) {
  int lo = 0, hi = n;
  while (lo < hi) {
    int mid = (lo + hi) >> 1;
    if (a[mid] < key) lo = mid + 1; else hi = mid;
  }
  return lo;
}

__global__ void pool_kernel(const float* __restrict__ h2, const int* __restrict__ batch,
                            float* __restrict__ pooled, int n) {
  int g = blockIdx.x, t = threadIdx.x;
  int lo = lower_bound_i(batch, n, g);
  int hi = lower_bound_i(batch, n, g + 1);
  float s = 0.f;
  for (int i = lo; i < hi; ++i) s += h2[(size_t)i * HC + t];
  float cnt = (float)(hi - lo);
  pooled[g * HC + t] = s / fmaxf(cnt, 1.0f);
}

// ---------------- final linear [G,256]@[256,10] ----------------
__global__ void final_kernel(const float* __restrict__ pooled, const float* __restrict__ Wf,
                             const float* __restrict__ bf, float* __restrict__ out) {
  int g = blockIdx.x, t = threadIdx.x;
  __shared__ float p[HC];
  p[t] = pooled[g * HC + t];
  __syncthreads();
  if (t < 10) {
    float s = bf[t];
    for (int c = 0; c < HC; ++c) s += p[c] * Wf[c * 10 + t];
    out[g * 10 + t] = s;
  }
}

extern "C" void kernel_launch(void* const* d_in, const int* in_sizes, int n_in,
                              void* d_out, int out_size, void* d_ws, size_t ws_size,
                              hipStream_t stream) {
  const float* x    = (const float*)d_in[0];
  const int*   ei   = (const int*)d_in[1];
  // d_in[2] = edge_weight (unused by reference)
  const int*   batch = (const int*)d_in[3];
  const float* W1   = (const float*)d_in[4];
  const float* as1  = (const float*)d_in[5];
  const float* ad1  = (const float*)d_in[6];
  const float* b1   = (const float*)d_in[7];
  const float* W2   = (const float*)d_in[8];
  const float* as2  = (const float*)d_in[9];
  const float* ad2  = (const float*)d_in[10];
  const float* b2   = (const float*)d_in[11];
  const float* Wf   = (const float*)d_in[12];
  const float* bf   = (const float*)d_in[13];
  float* out = (float*)d_out;

  const int N = in_sizes[0] / HC;  // 50000
  const int E = in_sizes[1] / 2;   // 800000

  // workspace layout
  float* bufA = (float*)d_ws;                       // N*256 (projected features)
  float* bufB = bufA + (size_t)N * HC;              // N*256 (activations)
  float* asrc = bufB + (size_t)N * HC;              // N*4
  float* adst = asrc + (size_t)N * HEADS;           // N*4
  int* counts = (int*)(adst + (size_t)N * HEADS);   // N
  int* row_ptr = counts + N;                        // N+1
  int* cursor = row_ptr + N + 1;                    // N
  int* srcs = cursor + N;                           // E+N

  // CSR build (same for both layers)
  fill_counts_kernel<<<(N + 255) / 256, 256, 0, stream>>>(counts, N);
  hist_kernel<<<(E + 255) / 256, 256, 0, stream>>>(ei, counts, E);
  scan_kernel<<<1, 256, 0, stream>>>(counts, row_ptr, cursor, N);
  scatter_kernel<<<(E + N + 255) / 256, 256, 0, stream>>>(ei, cursor, srcs, E, N);

  dim3 ggrid(HC / BN, (N + BM - 1) / BM);

  // layer 1
  gemm_kernel<<<ggrid, 256, 0, stream>>>(x, W1, bufA, N);
  att_kernel<<<N, 256, 0, stream>>>(bufA, as1, ad1, asrc, adst);
  aggregate_kernel<<<N, 256, 0, stream>>>(bufA, asrc, adst, row_ptr, srcs, b1, bufB);

  // layer 2
  gemm_kernel<<<ggrid, 256, 0, stream>>>(bufB, W2, bufA, N);
  att_kernel<<<N, 256, 0, stream>>>(bufA, as2, ad2, asrc, adst);
  aggregate_kernel<<<N, 256, 0, stream>>>(bufA, asrc, adst, row_ptr, srcs, b2, bufB);

  // pooling + classifier
  pool_kernel<<<GG, 256, 0, stream>>>(bufB, batch, out + GG * 10, N);
  final_kernel<<<GG, 256, 0, stream>>>(out + GG * 10, Wf, bf, out);
}

// Round 2
// 860.593 us; speedup vs baseline: 1.3736x; 1.3736x over previous
//
#include <hip/hip_runtime.h>
#include <math.h>

#define HEADS 4
#define HID 64
#define HC 256
#define NEG_SLOPE 0.2f
#define GG 128

// ---------------- CSR build (counting sort by dst) ----------------
__global__ void fill_counts_kernel(int* counts, int n) {
  int i = blockIdx.x * 256 + threadIdx.x;
  if (i < n) counts[i] = 1;  // every node has one self loop
}

__global__ void hist_kernel(const int* __restrict__ ei, int* counts, int E) {
  int e = blockIdx.x * 256 + threadIdx.x;
  if (e < E) atomicAdd(&counts[ei[E + e]], 1);
}

__global__ void scan_kernel(const int* __restrict__ counts, int* row_ptr, int* cursor, int n) {
  __shared__ int s_sums[256];
  int t = threadIdx.x;
  int chunk = (n + 255) / 256;
  int lo = t * chunk;
  int hi = lo + chunk;
  if (lo > n) lo = n;
  if (hi > n) hi = n;
  int s = 0;
  int i = lo;
  // vectorized body (lo is a multiple of 4 when chunk is; safe generic fallback below)
  if (((lo & 3) == 0)) {
    for (; i + 4 <= hi; i += 4) {
      int4 v = *(const int4*)&counts[i];
      s += v.x + v.y + v.z + v.w;
    }
  }
  for (; i < hi; ++i) s += counts[i];
  s_sums[t] = s;
  __syncthreads();
  for (int off = 1; off < 256; off <<= 1) {
    int v = (t >= off) ? s_sums[t - off] : 0;
    __syncthreads();
    s_sums[t] += v;
    __syncthreads();
  }
  int run = (t == 0) ? 0 : s_sums[t - 1];
  for (int j = lo; j < hi; ++j) {
    row_ptr[j] = run;
    cursor[j] = run;
    run += counts[j];
  }
  if (t == 255) row_ptr[n] = run;
}

__global__ void scatter_kernel(const int* __restrict__ ei, int* cursor, int* srcs, int E, int n) {
  int i = blockIdx.x * 256 + threadIdx.x;
  if (i >= E + n) return;
  int s, d;
  if (i < E) { s = ei[i]; d = ei[E + i]; }
  else       { s = i - E; d = s; }
  int pos = atomicAdd(&cursor[d], 1);
  srcs[pos] = s;
}

// ---------------- fp32 GEMM: C[M,256] = A[M,256] @ B[256,256] ----------------
#define BM 128
#define BN 128
#define BK 8
__global__ __launch_bounds__(256) void gemm_kernel(const float* __restrict__ A,
                                                   const float* __restrict__ B,
                                                   float* __restrict__ C, int M) {
  __shared__ float As[BK][BM + 4];
  __shared__ float Bs[BK][BN + 4];
  int tid = threadIdx.x;
  int tx = tid & 15, ty = tid >> 4;
  int r0 = blockIdx.y * BM;
  int c0 = blockIdx.x * BN;

  float acc[8][8];
#pragma unroll
  for (int i = 0; i < 8; ++i)
#pragma unroll
    for (int j = 0; j < 8; ++j) acc[i][j] = 0.0f;

  int a_row = tid >> 1;        // 0..127
  int a_c4 = (tid & 1) * 4;    // 0 or 4
  int b_k = tid >> 5;          // 0..7
  int b_c = (tid & 31) * 4;    // 0..124

  for (int k0 = 0; k0 < 256; k0 += BK) {
    float4 av = make_float4(0.f, 0.f, 0.f, 0.f);
    int gr = r0 + a_row;
    if (gr < M) av = *(const float4*)&A[(size_t)gr * 256 + k0 + a_c4];
    As[a_c4 + 0][a_row] = av.x;
    As[a_c4 + 1][a_row] = av.y;
    As[a_c4 + 2][a_row] = av.z;
    As[a_c4 + 3][a_row] = av.w;
    float4 bv = *(const float4*)&B[(size_t)(k0 + b_k) * 256 + c0 + b_c];
    *(float4*)&Bs[b_k][b_c] = bv;
    __syncthreads();
#pragma unroll
    for (int k = 0; k < BK; ++k) {
      float ar[8], br[8];
      float4 a0 = *(float4*)&As[k][ty * 8];
      float4 a1 = *(float4*)&As[k][ty * 8 + 4];
      float4 b0 = *(float4*)&Bs[k][tx * 8];
      float4 b1 = *(float4*)&Bs[k][tx * 8 + 4];
      ar[0] = a0.x; ar[1] = a0.y; ar[2] = a0.z; ar[3] = a0.w;
      ar[4] = a1.x; ar[5] = a1.y; ar[6] = a1.z; ar[7] = a1.w;
      br[0] = b0.x; br[1] = b0.y; br[2] = b0.z; br[3] = b0.w;
      br[4] = b1.x; br[5] = b1.y; br[6] = b1.z; br[7] = b1.w;
#pragma unroll
      for (int i = 0; i < 8; ++i)
#pragma unroll
        for (int j = 0; j < 8; ++j) acc[i][j] += ar[i] * br[j];
    }
    __syncthreads();
  }

#pragma unroll
  for (int i = 0; i < 8; ++i) {
    int gr = r0 + ty * 8 + i;
    if (gr < M) {
      float4 v0 = make_float4(acc[i][0], acc[i][1], acc[i][2], acc[i][3]);
      float4 v1 = make_float4(acc[i][4], acc[i][5], acc[i][6], acc[i][7]);
      *(float4*)&C[(size_t)gr * 256 + c0 + tx * 8] = v0;
      *(float4*)&C[(size_t)gr * 256 + c0 + tx * 8 + 4] = v1;
    }
  }
}

// ---------------- per-node attention scalars ----------------
__global__ void att_kernel(const float* __restrict__ h, const float* __restrict__ att_src,
                           const float* __restrict__ att_dst, float* __restrict__ asrc,
                           float* __restrict__ adst) {
  int n = blockIdx.x, t = threadIdx.x;
  float v = h[(size_t)n * HC + t];
  float ps = v * att_src[t];
  float pd = v * att_dst[t];
  for (int o = 32; o >= 1; o >>= 1) {
    ps += __shfl_xor(ps, o, 64);
    pd += __shfl_xor(pd, o, 64);
  }
  if ((t & 63) == 0) {
    int head = t >> 6;
    asrc[n * HEADS + head] = ps;
    adst[n * HEADS + head] = pd;
  }
}

__device__ __forceinline__ float lrelu(float x) { return x > 0.f ? x : NEG_SLOPE * x; }

// ---------------- segment softmax + aggregation: ONE WAVE PER NODE ----------------
// block = 256 threads = 4 waves; wave w handles node blockIdx.x*4 + w.
// No LDS, no __syncthreads. Lane owns 4 channels (float4).
__global__ __launch_bounds__(256) void aggregate_kernel(
    const float* __restrict__ hproj, const float* __restrict__ asrc,
    const float* __restrict__ adst, const int* __restrict__ row_ptr,
    const int* __restrict__ srcs, const float* __restrict__ bias,
    float* __restrict__ hout, int N) {
  int wave = threadIdx.x >> 6;
  int lane = threadIdx.x & 63;
  int node = blockIdx.x * 4 + wave;
  if (node >= N) return;

  int begin = row_ptr[node];
  int end = row_ptr[node + 1];
  int deg = end - begin;

  const float4* asrc4 = (const float4*)asrc;
  const float4* adst4 = (const float4*)adst;
  float4 ad = adst4[node];

  // register-cache src ids for first 64 edges
  int s_reg = (lane < deg) ? srcs[begin + lane] : 0;

  // ---- pass 1: per-head max of e = lrelu(asrc[s] + adst[n]) ----
  float m0 = -3.402823466e38f, m1 = m0, m2 = m0, m3 = m0;
  float4 e_reg = make_float4(m0, m0, m0, m0);  // cached e for first 64 edges
  for (int base = 0; base < deg; base += 64) {
    int idx = base + lane;
    float e0 = -3.402823466e38f, e1 = e0, e2 = e0, e3 = e0;
    if (idx < deg) {
      int s = (base == 0) ? s_reg : srcs[begin + idx];
      float4 a = asrc4[s];
      e0 = lrelu(a.x + ad.x);
      e1 = lrelu(a.y + ad.y);
      e2 = lrelu(a.z + ad.z);
      e3 = lrelu(a.w + ad.w);
    }
    if (base == 0) e_reg = make_float4(e0, e1, e2, e3);
    m0 = fmaxf(m0, e0); m1 = fmaxf(m1, e1);
    m2 = fmaxf(m2, e2); m3 = fmaxf(m3, e3);
  }
#pragma unroll
  for (int o = 1; o < 64; o <<= 1) {
    m0 = fmaxf(m0, __shfl_xor(m0, o, 64));
    m1 = fmaxf(m1, __shfl_xor(m1, o, 64));
    m2 = fmaxf(m2, __shfl_xor(m2, o, 64));
    m3 = fmaxf(m3, __shfl_xor(m3, o, 64));
  }

  // ---- pass 2: per-head sum of exp(e - m) ----
  float d0 = 0.f, d1 = 0.f, d2 = 0.f, d3 = 0.f;
  for (int base = 0; base < deg; base += 64) {
    int idx = base + lane;
    float e0, e1, e2, e3;
    if (base == 0) {
      e0 = e_reg.x; e1 = e_reg.y; e2 = e_reg.z; e3 = e_reg.w;
    } else {
      e0 = -3.402823466e38f; e1 = e0; e2 = e0; e3 = e0;
      if (idx < deg) {
        int s = srcs[begin + idx];
        float4 a = asrc4[s];
        e0 = lrelu(a.x + ad.x);
        e1 = lrelu(a.y + ad.y);
        e2 = lrelu(a.z + ad.z);
        e3 = lrelu(a.w + ad.w);
      }
    }
    d0 += __expf(e0 - m0); d1 += __expf(e1 - m1);
    d2 += __expf(e2 - m2); d3 += __expf(e3 - m3);
  }
#pragma unroll
  for (int o = 1; o < 64; o <<= 1) {
    d0 += __shfl_xor(d0, o, 64);
    d1 += __shfl_xor(d1, o, 64);
    d2 += __shfl_xor(d2, o, 64);
    d3 += __shfl_xor(d3, o, 64);
  }

  // ---- pass 3: weighted accumulation; lane owns channels [lane*4, lane*4+4) ----
  int head = lane >> 4;  // 4 channels of a lane are all in one head
  float mh = (head == 0) ? m0 : (head == 1) ? m1 : (head == 2) ? m2 : m3;
  float dh = (head == 0) ? d0 : (head == 1) ? d1 : (head == 2) ? d2 : d3;
  float adh = (head == 0) ? ad.x : (head == 1) ? ad.y : (head == 2) ? ad.z : ad.w;
  float rdh = 1.0f / (dh + 1e-16f);

  const float4* hproj4 = (const float4*)hproj;
  float4 acc = make_float4(0.f, 0.f, 0.f, 0.f);
  for (int i = 0; i < deg; ++i) {
    int s = (i < 64) ? __shfl(s_reg, i, 64) : srcs[begin + i];
    float ash = asrc[s * HEADS + head];
    float alpha = __expf(lrelu(ash + adh) - mh) * rdh;
    float4 hv = hproj4[(size_t)s * 64 + lane];
    acc.x += alpha * hv.x;
    acc.y += alpha * hv.y;
    acc.z += alpha * hv.z;
    acc.w += alpha * hv.w;
  }
  float4 bv = ((const float4*)bias)[lane];
  float4 o;
  o.x = fmaxf(acc.x + bv.x, 0.f);
  o.y = fmaxf(acc.y + bv.y, 0.f);
  o.z = fmaxf(acc.z + bv.z, 0.f);
  o.w = fmaxf(acc.w + bv.w, 0.f);
  ((float4*)hout)[(size_t)node * 64 + lane] = o;
}

// ---------------- global mean pool (batch is sorted) ----------------
__device__ __forceinline__ int lower_bound_i(const int* a, int n, int key) {
  int lo = 0, hi = n;
  while (lo < hi) {
    int mid = (lo + hi) >> 1;
    if (a[mid] < key) lo = mid + 1; else hi = mid;
  }
  return lo;
}

__global__ __launch_bounds__(256) void pool_kernel(const float* __restrict__ h2,
                                                   const int* __restrict__ batch,
                                                   float* __restrict__ pooled, int n) {
  int g = blockIdx.x;
  int wave = threadIdx.x >> 6, lane = threadIdx.x & 63;
  int lo = lower_bound_i(batch, n, g);
  int hi = lower_bound_i(batch, n, g + 1);
  const float4* h4 = (const float4*)h2;
  float4 acc = make_float4(0.f, 0.f, 0.f, 0.f);
  for (int i = lo + wave; i < hi; i += 4) {
    float4 v = h4[(size_t)i * 64 + lane];
    acc.x += v.x; acc.y += v.y; acc.z += v.z; acc.w += v.w;
  }
  __shared__ float4 red[4][64];
  red[wave][lane] = acc;
  __syncthreads();
  if (wave == 0) {
    float4 a0 = red[0][lane], a1 = red[1][lane], a2 = red[2][lane], a3 = red[3][lane];
    float inv = 1.0f / fmaxf((float)(hi - lo), 1.0f);
    float4 o;
    o.x = (a0.x + a1.x + a2.x + a3.x) * inv;
    o.y = (a0.y + a1.y + a2.y + a3.y) * inv;
    o.z = (a0.z + a1.z + a2.z + a3.z) * inv;
    o.w = (a0.w + a1.w + a2.w + a3.w) * inv;
    ((float4*)pooled)[g * 64 + lane] = o;
  }
}

// ---------------- final linear [G,256]@[256,10] ----------------
__global__ void final_kernel(const float* __restrict__ pooled, const float* __restrict__ Wf,
                             const float* __restrict__ bf, float* __restrict__ out) {
  int g = blockIdx.x, t = threadIdx.x;
  __shared__ float p[HC];
  p[t] = pooled[g * HC + t];
  __syncthreads();
  if (t < 10) {
    float s = bf[t];
    for (int c = 0; c < HC; ++c) s += p[c] * Wf[c * 10 + t];
    out[g * 10 + t] = s;
  }
}

extern "C" void kernel_launch(void* const* d_in, const int* in_sizes, int n_in,
                              void* d_out, int out_size, void* d_ws, size_t ws_size,
                              hipStream_t stream) {
  const float* x    = (const float*)d_in[0];
  const int*   ei   = (const int*)d_in[1];
  // d_in[2] = edge_weight (unused by reference)
  const int*   batch = (const int*)d_in[3];
  const float* W1   = (const float*)d_in[4];
  const float* as1  = (const float*)d_in[5];
  const float* ad1  = (const float*)d_in[6];
  const float* b1   = (const float*)d_in[7];
  const float* W2   = (const float*)d_in[8];
  const float* as2  = (const float*)d_in[9];
  const float* ad2  = (const float*)d_in[10];
  const float* b2   = (const float*)d_in[11];
  const float* Wf   = (const float*)d_in[12];
  const float* bf   = (const float*)d_in[13];
  float* out = (float*)d_out;

  const int N = in_sizes[0] / HC;  // 50000
  const int E = in_sizes[1] / 2;   // 800000

  // workspace layout
  float* bufA = (float*)d_ws;                       // N*256 (projected features)
  float* bufB = bufA + (size_t)N * HC;              // N*256 (activations)
  float* asrc = bufB + (size_t)N * HC;              // N*4
  float* adst = asrc + (size_t)N * HEADS;           // N*4
  int* counts = (int*)(adst + (size_t)N * HEADS);   // N
  int* row_ptr = counts + N;                        // N+1
  int* cursor = row_ptr + N + 1;                    // N
  int* srcs = cursor + N;                           // E+N

  // CSR build (same for both layers)
  fill_counts_kernel<<<(N + 255) / 256, 256, 0, stream>>>(counts, N);
  hist_kernel<<<(E + 255) / 256, 256, 0, stream>>>(ei, counts, E);
  scan_kernel<<<1, 256, 0, stream>>>(counts, row_ptr, cursor, N);
  scatter_kernel<<<(E + N + 255) / 256, 256, 0, stream>>>(ei, cursor, srcs, E, N);

  dim3 ggrid(HC / BN, (N + BM - 1) / BM);
  int agg_blocks = (N + 3) / 4;

  // layer 1
  gemm_kernel<<<ggrid, 256, 0, stream>>>(x, W1, bufA, N);
  att_kernel<<<N, 256, 0, stream>>>(bufA, as1, ad1, asrc, adst);
  aggregate_kernel<<<agg_blocks, 256, 0, stream>>>(bufA, asrc, adst, row_ptr, srcs, b1, bufB, N);

  // layer 2
  gemm_kernel<<<ggrid, 256, 0, stream>>>(bufB, W2, bufA, N);
  att_kernel<<<N, 256, 0, stream>>>(bufA, as2, ad2, asrc, adst);
  aggregate_kernel<<<agg_blocks, 256, 0, stream>>>(bufA, asrc, adst, row_ptr, srcs, b2, bufB, N);

  // pooling + classifier
  pool_kernel<<<GG, 256, 0, stream>>>(bufB, batch, out + GG * 10, N);
  final_kernel<<<GG, 256, 0, stream>>>(out + GG * 10, Wf, bf, out);
}

// Round 3
// 759.668 us; speedup vs baseline: 1.5561x; 1.1329x over previous
//
#include <hip/hip_runtime.h>
#include <math.h>

#define HEADS 4
#define HID 64
#define HC 256
#define NEG_SLOPE 0.2f
#define GG 128

typedef __attribute__((ext_vector_type(8))) short short8;
typedef __attribute__((ext_vector_type(4))) float floatx4;

__device__ __forceinline__ unsigned short f2bf(float f) {
  unsigned u = __float_as_uint(f);
  unsigned r = (u + 0x7FFFu + ((u >> 16) & 1u)) >> 16;  // RNE
  return (unsigned short)r;
}
__device__ __forceinline__ float bf2f(unsigned short h) {
  return __uint_as_float(((unsigned)h) << 16);
}

// ---------------- CSR build (counting sort by dst) ----------------
__global__ void fill_counts_kernel(int* counts, int n) {
  int i = blockIdx.x * 256 + threadIdx.x;
  if (i < n) counts[i] = 1;  // self loop
}

__global__ void hist_kernel(const int* __restrict__ ei, int* counts, int E) {
  int e = blockIdx.x * 256 + threadIdx.x;
  if (e < E) atomicAdd(&counts[ei[E + e]], 1);
}

__global__ void scan_kernel(const int* __restrict__ counts, int* row_ptr, int* cursor, int n) {
  __shared__ int s_sums[256];
  int t = threadIdx.x;
  int chunk = (n + 255) / 256;
  int lo = t * chunk, hi = lo + chunk;
  if (lo > n) lo = n;
  if (hi > n) hi = n;
  int s = 0;
  int i = lo;
  if ((lo & 3) == 0) {
    for (; i + 4 <= hi; i += 4) {
      int4 v = *(const int4*)&counts[i];
      s += v.x + v.y + v.z + v.w;
    }
  }
  for (; i < hi; ++i) s += counts[i];
  s_sums[t] = s;
  __syncthreads();
  for (int off = 1; off < 256; off <<= 1) {
    int v = (t >= off) ? s_sums[t - off] : 0;
    __syncthreads();
    s_sums[t] += v;
    __syncthreads();
  }
  int run = (t == 0) ? 0 : s_sums[t - 1];
  for (int j = lo; j < hi; ++j) {
    row_ptr[j] = run;
    cursor[j] = run;
    run += counts[j];
  }
  if (t == 255) row_ptr[n] = run;
}

__global__ void scatter_kernel(const int* __restrict__ ei, int* cursor, int* srcs, int E, int n) {
  int i = blockIdx.x * 256 + threadIdx.x;
  if (i >= E + n) return;
  int s, d;
  if (i < E) { s = ei[i]; d = ei[E + i]; }
  else       { s = i - E; d = s; }
  int pos = atomicAdd(&cursor[d], 1);
  srcs[pos] = s;
}

// ---------------- B pre-convert: fp32 [256,256] -> bf16 hi/lo TRANSPOSED [n][k] ----------------
__global__ void convertB_kernel(const float* __restrict__ B, unsigned short* __restrict__ Bth,
                                unsigned short* __restrict__ Btl) {
  int k = blockIdx.x, n = threadIdx.x;
  float v = B[k * HC + n];
  unsigned short h = f2bf(v);
  unsigned short l = f2bf(v - bf2f(h));
  Bth[n * HC + k] = h;
  Btl[n * HC + k] = l;
}

// ---------------- bf16-split MFMA GEMM: C[M,256] = A[M,256](fp32) @ B ----------------
// grid (2, ceil(M/128)), block 256 (4 waves, 2x2 of 64x64)
#define LDA 40  // padded k-stride in shorts (80B, 16B aligned, 2-way-bank-free)
__global__ __launch_bounds__(256) void gemm_kernel(
    const float* __restrict__ A, const unsigned short* __restrict__ Bth,
    const unsigned short* __restrict__ Btl, float* __restrict__ C, int M) {
  __shared__ unsigned short sAh[128 * LDA];
  __shared__ unsigned short sAl[128 * LDA];
  __shared__ unsigned short sBh[128 * LDA];
  __shared__ unsigned short sBl[128 * LDA];

  int t = threadIdx.x;
  int lane = t & 63, wave = t >> 6;
  int wm = wave >> 1, wn = wave & 1;  // wave tile: rows wm*64, cols wn*64
  int q = lane >> 4, mrow = lane & 15;
  int r0 = blockIdx.y * 128;
  int c0 = blockIdx.x * 128;

  int arow = t >> 1;          // 0..127
  int aofs = (t & 1) * 16;    // 0 / 16
  bool avalid = (r0 + arow) < M;
  const float* Ag = A + (size_t)(r0 + arow) * HC + aofs;
  const unsigned short* Bgh = Bth + (size_t)(c0 + arow) * HC + aofs;
  const unsigned short* Bgl = Btl + (size_t)(c0 + arow) * HC + aofs;

  floatx4 acc[4][4];
#pragma unroll
  for (int i = 0; i < 4; ++i)
#pragma unroll
    for (int j = 0; j < 4; ++j) acc[i][j] = (floatx4)(0.0f);

  for (int k0 = 0; k0 < HC; k0 += 32) {
    __syncthreads();
    // stage A (fp32 -> bf16 hi/lo)
#pragma unroll
    for (int c = 0; c < 16; c += 4) {
      float4 v = make_float4(0.f, 0.f, 0.f, 0.f);
      if (avalid) v = *(const float4*)(Ag + k0 + c);
      unsigned short h0 = f2bf(v.x), h1 = f2bf(v.y), h2 = f2bf(v.z), h3 = f2bf(v.w);
      ushort4 hv = make_ushort4(h0, h1, h2, h3);
      ushort4 lv = make_ushort4(f2bf(v.x - bf2f(h0)), f2bf(v.y - bf2f(h1)),
                                f2bf(v.z - bf2f(h2)), f2bf(v.w - bf2f(h3)));
      *(ushort4*)&sAh[arow * LDA + aofs + c] = hv;
      *(ushort4*)&sAl[arow * LDA + aofs + c] = lv;
    }
    // stage B (already bf16, transposed [n][k])
    *(int4*)&sBh[arow * LDA + aofs] = *(const int4*)(Bgh + k0);
    *(int4*)&sBh[arow * LDA + aofs + 8] = *(const int4*)(Bgh + k0 + 8);
    *(int4*)&sBl[arow * LDA + aofs] = *(const int4*)(Bgl + k0);
    *(int4*)&sBl[arow * LDA + aofs + 8] = *(const int4*)(Bgl + k0 + 8);
    __syncthreads();

    short8 ah[4], al[4], bh[4], bl[4];
#pragma unroll
    for (int i = 0; i < 4; ++i) {
      int ar = (wm * 64 + i * 16 + mrow) * LDA + q * 8;
      int br = (wn * 64 + i * 16 + mrow) * LDA + q * 8;
      ah[i] = *(short8*)&sAh[ar];
      al[i] = *(short8*)&sAl[ar];
      bh[i] = *(short8*)&sBh[br];
      bl[i] = *(short8*)&sBl[br];
    }
#pragma unroll
    for (int i = 0; i < 4; ++i)
#pragma unroll
      for (int j = 0; j < 4; ++j) {
        acc[i][j] = __builtin_amdgcn_mfma_f32_16x16x32_bf16(ah[i], bh[j], acc[i][j], 0, 0, 0);
        acc[i][j] = __builtin_amdgcn_mfma_f32_16x16x32_bf16(ah[i], bl[j], acc[i][j], 0, 0, 0);
        acc[i][j] = __builtin_amdgcn_mfma_f32_16x16x32_bf16(al[i], bh[j], acc[i][j], 0, 0, 0);
      }
  }

  // epilogue: C/D layout col=lane&15, row=(lane>>4)*4+reg
#pragma unroll
  for (int i = 0; i < 4; ++i) {
#pragma unroll
    for (int j = 0; j < 4; ++j) {
      int col = c0 + wn * 64 + j * 16 + mrow;
#pragma unroll
      for (int r = 0; r < 4; ++r) {
        int gr = r0 + wm * 64 + i * 16 + q * 4 + r;
        if (gr < M) C[(size_t)gr * HC + col] = acc[i][j][r];
      }
    }
  }
}

// ---------------- per-node attention scalars ----------------
__global__ void att_kernel(const float* __restrict__ h, const float* __restrict__ att_src,
                           const float* __restrict__ att_dst, float* __restrict__ asrc,
                           float* __restrict__ adst) {
  int n = blockIdx.x, t = threadIdx.x;
  float v = h[(size_t)n * HC + t];
  float ps = v * att_src[t];
  float pd = v * att_dst[t];
  for (int o = 32; o >= 1; o >>= 1) {
    ps += __shfl_xor(ps, o, 64);
    pd += __shfl_xor(pd, o, 64);
  }
  if ((t & 63) == 0) {
    int head = t >> 6;
    asrc[n * HEADS + head] = ps;
    adst[n * HEADS + head] = pd;
  }
}

__device__ __forceinline__ float lrelu(float x) { return x > 0.f ? x : NEG_SLOPE * x; }

// ---------------- segment softmax + aggregation: ONE WAVE PER NODE ----------------
// Single stats pass (alpha cached in wave-private LDS), 4x-unrolled gather.
__global__ __launch_bounds__(256) void aggregate_kernel(
    const float* __restrict__ hproj, const float* __restrict__ asrc,
    const float* __restrict__ adst, const int* __restrict__ row_ptr,
    const int* __restrict__ srcs, const float* __restrict__ bias,
    float* __restrict__ hout, int N) {
  __shared__ float s_alpha[4][64 * 4];
  __shared__ int s_src[4][64];

  int wave = threadIdx.x >> 6;
  int lane = threadIdx.x & 63;
  int node = blockIdx.x * 4 + wave;
  if (node >= N) return;

  int begin = row_ptr[node];
  int end = row_ptr[node + 1];
  int deg = end - begin;
  int nb = deg < 64 ? deg : 64;

  const float4* asrc4 = (const float4*)asrc;
  float4 ad = ((const float4*)adst)[node];

  // ---- stats (first 64 edges live in registers) ----
  const float NEGINF = -3.402823466e38f;
  int s0 = 0;
  float4 e0 = make_float4(NEGINF, NEGINF, NEGINF, NEGINF);
  if (lane < nb) {
    s0 = srcs[begin + lane];
    float4 a = asrc4[s0];
    e0.x = lrelu(a.x + ad.x);
    e0.y = lrelu(a.y + ad.y);
    e0.z = lrelu(a.z + ad.z);
    e0.w = lrelu(a.w + ad.w);
  }
  float m0 = e0.x, m1 = e0.y, m2 = e0.z, m3 = e0.w;
  // rare: extra batches contribute to max
  for (int base = 64; base < deg; base += 64) {
    int idx = base + lane;
    if (idx < deg) {
      int s = srcs[begin + idx];
      float4 a = asrc4[s];
      m0 = fmaxf(m0, lrelu(a.x + ad.x));
      m1 = fmaxf(m1, lrelu(a.y + ad.y));
      m2 = fmaxf(m2, lrelu(a.z + ad.z));
      m3 = fmaxf(m3, lrelu(a.w + ad.w));
    }
  }
#pragma unroll
  for (int o = 1; o < 64; o <<= 1) {
    m0 = fmaxf(m0, __shfl_xor(m0, o, 64));
    m1 = fmaxf(m1, __shfl_xor(m1, o, 64));
    m2 = fmaxf(m2, __shfl_xor(m2, o, 64));
    m3 = fmaxf(m3, __shfl_xor(m3, o, 64));
  }
  float ex0 = (lane < nb) ? __expf(e0.x - m0) : 0.f;
  float ex1 = (lane < nb) ? __expf(e0.y - m1) : 0.f;
  float ex2 = (lane < nb) ? __expf(e0.z - m2) : 0.f;
  float ex3 = (lane < nb) ? __expf(e0.w - m3) : 0.f;
  float d0 = ex0, d1 = ex1, d2 = ex2, d3 = ex3;
  for (int base = 64; base < deg; base += 64) {
    int idx = base + lane;
    if (idx < deg) {
      int s = srcs[begin + idx];
      float4 a = asrc4[s];
      d0 += __expf(lrelu(a.x + ad.x) - m0);
      d1 += __expf(lrelu(a.y + ad.y) - m1);
      d2 += __expf(lrelu(a.z + ad.z) - m2);
      d3 += __expf(lrelu(a.w + ad.w) - m3);
    }
  }
#pragma unroll
  for (int o = 1; o < 64; o <<= 1) {
    d0 += __shfl_xor(d0, o, 64);
    d1 += __shfl_xor(d1, o, 64);
    d2 += __shfl_xor(d2, o, 64);
    d3 += __shfl_xor(d3, o, 64);
  }
  float r0 = 1.0f / (d0 + 1e-16f);
  float r1 = 1.0f / (d1 + 1e-16f);
  float r2 = 1.0f / (d2 + 1e-16f);
  float r3 = 1.0f / (d3 + 1e-16f);

  // park alpha + src ids in wave-private LDS (no barrier needed)
  *(float4*)&s_alpha[wave][lane * 4] = make_float4(ex0 * r0, ex1 * r1, ex2 * r2, ex3 * r3);
  s_src[wave][lane] = s0;

  // ---- gather: lane owns 4 channels; 4 independent accumulators ----
  int head = lane >> 4;
  float mh = (head == 0) ? m0 : (head == 1) ? m1 : (head == 2) ? m2 : m3;
  float rdh = (head == 0) ? r0 : (head == 1) ? r1 : (head == 2) ? r2 : r3;
  float adh = (head == 0) ? ad.x : (head == 1) ? ad.y : (head == 2) ? ad.z : ad.w;

  const float4* hproj4 = (const float4*)hproj;
  float4 accA = make_float4(0.f, 0.f, 0.f, 0.f);
  float4 accB = accA, accC = accA, accD = accA;
  int i = 0;
  for (; i + 4 <= nb; i += 4) {
    int sa = s_src[wave][i];
    int sb = s_src[wave][i + 1];
    int sc = s_src[wave][i + 2];
    int sd = s_src[wave][i + 3];
    float aa = s_alpha[wave][i * 4 + head];
    float ab = s_alpha[wave][(i + 1) * 4 + head];
    float ac = s_alpha[wave][(i + 2) * 4 + head];
    float ad_ = s_alpha[wave][(i + 3) * 4 + head];
    float4 h0 = hproj4[(size_t)sa * 64 + lane];
    float4 h1 = hproj4[(size_t)sb * 64 + lane];
    float4 h2 = hproj4[(size_t)sc * 64 + lane];
    float4 h3 = hproj4[(size_t)sd * 64 + lane];
    accA.x += aa * h0.x; accA.y += aa * h0.y; accA.z += aa * h0.z; accA.w += aa * h0.w;
    accB.x += ab * h1.x; accB.y += ab * h1.y; accB.z += ab * h1.z; accB.w += ab * h1.w;
    accC.x += ac * h2.x; accC.y += ac * h2.y; accC.z += ac * h2.z; accC.w += ac * h2.w;
    accD.x += ad_ * h3.x; accD.y += ad_ * h3.y; accD.z += ad_ * h3.z; accD.w += ad_ * h3.w;
  }
  for (; i < nb; ++i) {
    int s = s_src[wave][i];
    float a = s_alpha[wave][i * 4 + head];
    float4 hv = hproj4[(size_t)s * 64 + lane];
    accA.x += a * hv.x; accA.y += a * hv.y; accA.z += a * hv.z; accA.w += a * hv.w;
  }
  // rare: edges beyond 64 — recompute alpha on the fly
  for (int i2 = 64; i2 < deg; ++i2) {
    int s = srcs[begin + i2];
    float ash = asrc[s * HEADS + head];
    float a = __expf(lrelu(ash + adh) - mh) * rdh;
    float4 hv = hproj4[(size_t)s * 64 + lane];
    accA.x += a * hv.x; accA.y += a * hv.y; accA.z += a * hv.z; accA.w += a * hv.w;
  }

  float4 acc;
  acc.x = (accA.x + accB.x) + (accC.x + accD.x);
  acc.y = (accA.y + accB.y) + (accC.y + accD.y);
  acc.z = (accA.z + accB.z) + (accC.z + accD.z);
  acc.w = (accA.w + accB.w) + (accC.w + accD.w);
  float4 bv = ((const float4*)bias)[lane];
  float4 o;
  o.x = fmaxf(acc.x + bv.x, 0.f);
  o.y = fmaxf(acc.y + bv.y, 0.f);
  o.z = fmaxf(acc.z + bv.z, 0.f);
  o.w = fmaxf(acc.w + bv.w, 0.f);
  ((float4*)hout)[(size_t)node * 64 + lane] = o;
}

// ---------------- global mean pool (batch is sorted) ----------------
__device__ __forceinline__ int lower_bound_i(const int* a, int n, int key) {
  int lo = 0, hi = n;
  while (lo < hi) {
    int mid = (lo + hi) >> 1;
    if (a[mid] < key) lo = mid + 1; else hi = mid;
  }
  return lo;
}

__global__ __launch_bounds__(256) void pool_kernel(const float* __restrict__ h2,
                                                   const int* __restrict__ batch,
                                                   float* __restrict__ pooled, int n) {
  int g = blockIdx.x;
  int wave = threadIdx.x >> 6, lane = threadIdx.x & 63;
  int lo = lower_bound_i(batch, n, g);
  int hi = lower_bound_i(batch, n, g + 1);
  const float4* h4 = (const float4*)h2;
  float4 acc = make_float4(0.f, 0.f, 0.f, 0.f);
  for (int i = lo + wave; i < hi; i += 4) {
    float4 v = h4[(size_t)i * 64 + lane];
    acc.x += v.x; acc.y += v.y; acc.z += v.z; acc.w += v.w;
  }
  __shared__ float4 red[4][64];
  red[wave][lane] = acc;
  __syncthreads();
  if (wave == 0) {
    float4 a0 = red[0][lane], a1 = red[1][lane], a2 = red[2][lane], a3 = red[3][lane];
    float inv = 1.0f / fmaxf((float)(hi - lo), 1.0f);
    float4 o;
    o.x = (a0.x + a1.x + a2.x + a3.x) * inv;
    o.y = (a0.y + a1.y + a2.y + a3.y) * inv;
    o.z = (a0.z + a1.z + a2.z + a3.z) * inv;
    o.w = (a0.w + a1.w + a2.w + a3.w) * inv;
    ((float4*)pooled)[g * 64 + lane] = o;
  }
}

// ---------------- final linear [G,256]@[256,10] ----------------
__global__ void final_kernel(const float* __restrict__ pooled, const float* __restrict__ Wf,
                             const float* __restrict__ bf, float* __restrict__ out) {
  int g = blockIdx.x, t = threadIdx.x;
  __shared__ float p[HC];
  p[t] = pooled[g * HC + t];
  __syncthreads();
  if (t < 10) {
    float s = bf[t];
    for (int c = 0; c < HC; ++c) s += p[c] * Wf[c * 10 + t];
    out[g * 10 + t] = s;
  }
}

extern "C" void kernel_launch(void* const* d_in, const int* in_sizes, int n_in,
                              void* d_out, int out_size, void* d_ws, size_t ws_size,
                              hipStream_t stream) {
  const float* x    = (const float*)d_in[0];
  const int*   ei   = (const int*)d_in[1];
  const int*   batch = (const int*)d_in[3];
  const float* W1   = (const float*)d_in[4];
  const float* as1  = (const float*)d_in[5];
  const float* ad1  = (const float*)d_in[6];
  const float* b1   = (const float*)d_in[7];
  const float* W2   = (const float*)d_in[8];
  const float* as2  = (const float*)d_in[9];
  const float* ad2  = (const float*)d_in[10];
  const float* b2   = (const float*)d_in[11];
  const float* Wf   = (const float*)d_in[12];
  const float* bf   = (const float*)d_in[13];
  float* out = (float*)d_out;

  const int N = in_sizes[0] / HC;  // 50000
  const int E = in_sizes[1] / 2;   // 800000

  // workspace layout
  float* bufA = (float*)d_ws;                       // N*256
  float* bufB = bufA + (size_t)N * HC;              // N*256
  float* asrc = bufB + (size_t)N * HC;              // N*4
  float* adst = asrc + (size_t)N * HEADS;           // N*4
  int* counts = (int*)(adst + (size_t)N * HEADS);   // N
  int* row_ptr = counts + N;                        // N+1
  int* cursor = row_ptr + N + 1;                    // N
  int* srcs = cursor + N;                           // E+N
  unsigned short* Bth = (unsigned short*)(srcs + E + N);  // 256*256
  unsigned short* Btl = Bth + HC * HC;                    // 256*256

  // CSR build
  fill_counts_kernel<<<(N + 255) / 256, 256, 0, stream>>>(counts, N);
  hist_kernel<<<(E + 255) / 256, 256, 0, stream>>>(ei, counts, E);
  scan_kernel<<<1, 256, 0, stream>>>(counts, row_ptr, cursor, N);
  scatter_kernel<<<(E + N + 255) / 256, 256, 0, stream>>>(ei, cursor, srcs, E, N);

  dim3 ggrid(2, (N + 127) / 128);
  int agg_blocks = (N + 3) / 4;

  // layer 1
  convertB_kernel<<<HC, HC, 0, stream>>>(W1, Bth, Btl);
  gemm_kernel<<<ggrid, 256, 0, stream>>>(x, Bth, Btl, bufA, N);
  att_kernel<<<N, 256, 0, stream>>>(bufA, as1, ad1, asrc, adst);
  aggregate_kernel<<<agg_blocks, 256, 0, stream>>>(bufA, asrc, adst, row_ptr, srcs, b1, bufB, N);

  // layer 2
  convertB_kernel<<<HC, HC, 0, stream>>>(W2, Bth, Btl);
  gemm_kernel<<<ggrid, 256, 0, stream>>>(bufB, Bth, Btl, bufA, N);
  att_kernel<<<N, 256, 0, stream>>>(bufA, as2, ad2, asrc, adst);
  aggregate_kernel<<<agg_blocks, 256, 0, stream>>>(bufA, asrc, adst, row_ptr, srcs, b2, bufB, N);

  // pooling + classifier
  pool_kernel<<<GG, 256, 0, stream>>>(bufB, batch, out + GG * 10, N);
  final_kernel<<<GG, 256, 0, stream>>>(out + GG * 10, Wf, bf, out);
}

// Round 4
// 588.517 us; speedup vs baseline: 2.0087x; 1.2908x over previous
//
#include <hip/hip_runtime.h>
#include <math.h>

#define HEADS 4
#define HID 64
#define HC 256
#define NEG_SLOPE 0.2f
#define GG 128

typedef __attribute__((ext_vector_type(8))) short short8;
typedef __attribute__((ext_vector_type(4))) float floatx4;

__device__ __forceinline__ unsigned short f2bf(float f) {
  unsigned u = __float_as_uint(f);
  unsigned r = (u + 0x7FFFu + ((u >> 16) & 1u)) >> 16;  // RNE
  return (unsigned short)r;
}
__device__ __forceinline__ float bf2f(unsigned short h) {
  return __uint_as_float(((unsigned)h) << 16);
}

// ---------------- CSR build (counting sort by dst) ----------------
__global__ void fill_counts_kernel(int* counts, int n) {
  int i = blockIdx.x * 256 + threadIdx.x;
  if (i < n) counts[i] = 1;  // self loop
}

__global__ void hist_kernel(const int* __restrict__ ei, int* counts, int E) {
  int e = blockIdx.x * 256 + threadIdx.x;
  if (e < E) atomicAdd(&counts[ei[E + e]], 1);
}

__global__ void scan_kernel(const int* __restrict__ counts, int* row_ptr, int* cursor, int n) {
  __shared__ int s_sums[256];
  int t = threadIdx.x;
  int chunk = (n + 255) / 256;
  int lo = t * chunk, hi = lo + chunk;
  if (lo > n) lo = n;
  if (hi > n) hi = n;
  int s = 0;
  int i = lo;
  if ((lo & 3) == 0) {
    for (; i + 4 <= hi; i += 4) {
      int4 v = *(const int4*)&counts[i];
      s += v.x + v.y + v.z + v.w;
    }
  }
  for (; i < hi; ++i) s += counts[i];
  s_sums[t] = s;
  __syncthreads();
  for (int off = 1; off < 256; off <<= 1) {
    int v = (t >= off) ? s_sums[t - off] : 0;
    __syncthreads();
    s_sums[t] += v;
    __syncthreads();
  }
  int run = (t == 0) ? 0 : s_sums[t - 1];
  for (int j = lo; j < hi; ++j) {
    row_ptr[j] = run;
    cursor[j] = run;
    run += counts[j];
  }
  if (t == 255) row_ptr[n] = run;
}

__global__ void scatter_kernel(const int* __restrict__ ei, int* cursor, int* srcs, int E, int n) {
  int i = blockIdx.x * 256 + threadIdx.x;
  if (i >= E + n) return;
  int s, d;
  if (i < E) { s = ei[i]; d = ei[E + i]; }
  else       { s = i - E; d = s; }
  int pos = atomicAdd(&cursor[d], 1);
  srcs[pos] = s;
}

// ---------------- B pre-convert: fp32 [256,256] -> bf16 hi/lo TRANSPOSED [n][k] ----------------
__global__ void convertB_kernel(const float* __restrict__ B, unsigned short* __restrict__ Bth,
                                unsigned short* __restrict__ Btl) {
  int k = blockIdx.x, n = threadIdx.x;
  float v = B[k * HC + n];
  unsigned short h = f2bf(v);
  unsigned short l = f2bf(v - bf2f(h));
  Bth[n * HC + k] = h;
  Btl[n * HC + k] = l;
}

// ---------------- bf16-split MFMA GEMM + fused att + bf16 C ----------------
// C_bf[M,256](bf16) = round_bf16( A[M,256](fp32) @ B );
// asrc[M,4], adst[M,4] = per-(row,head) dots of fp32 accum with att vectors.
// grid (2, ceil(M/128)), block 256 (4 waves, 2x2 of 64x64); each wave owns a
// full 64-col head stripe so the att dot is an in-wave reduction.
#define LDA 40  // padded k-stride in shorts (80B, 16B aligned)
__global__ __launch_bounds__(256) void gemm_kernel(
    const float* __restrict__ A, const unsigned short* __restrict__ Bth,
    const unsigned short* __restrict__ Btl, const float* __restrict__ att_src,
    const float* __restrict__ att_dst, unsigned short* __restrict__ Cb,
    float* __restrict__ asrc_o, float* __restrict__ adst_o, int M) {
  __shared__ unsigned short sAh[128 * LDA];
  __shared__ unsigned short sAl[128 * LDA];
  __shared__ unsigned short sBh[128 * LDA];
  __shared__ unsigned short sBl[128 * LDA];

  int t = threadIdx.x;
  int lane = t & 63, wave = t >> 6;
  int wm = wave >> 1, wn = wave & 1;
  int q = lane >> 4, mrow = lane & 15;
  int r0 = blockIdx.y * 128;
  int c0 = blockIdx.x * 128;

  int arow = t >> 1;
  int aofs = (t & 1) * 16;
  bool avalid = (r0 + arow) < M;
  const float* Ag = A + (size_t)(r0 + arow) * HC + aofs;
  const unsigned short* Bgh = Bth + (size_t)(c0 + arow) * HC + aofs;
  const unsigned short* Bgl = Btl + (size_t)(c0 + arow) * HC + aofs;

  floatx4 acc[4][4];
#pragma unroll
  for (int i = 0; i < 4; ++i)
#pragma unroll
    for (int j = 0; j < 4; ++j) acc[i][j] = (floatx4)(0.0f);

  for (int k0 = 0; k0 < HC; k0 += 32) {
    __syncthreads();
#pragma unroll
    for (int c = 0; c < 16; c += 4) {
      float4 v = make_float4(0.f, 0.f, 0.f, 0.f);
      if (avalid) v = *(const float4*)(Ag + k0 + c);
      unsigned short h0 = f2bf(v.x), h1 = f2bf(v.y), h2 = f2bf(v.z), h3 = f2bf(v.w);
      ushort4 hv = make_ushort4(h0, h1, h2, h3);
      ushort4 lv = make_ushort4(f2bf(v.x - bf2f(h0)), f2bf(v.y - bf2f(h1)),
                                f2bf(v.z - bf2f(h2)), f2bf(v.w - bf2f(h3)));
      *(ushort4*)&sAh[arow * LDA + aofs + c] = hv;
      *(ushort4*)&sAl[arow * LDA + aofs + c] = lv;
    }
    *(int4*)&sBh[arow * LDA + aofs] = *(const int4*)(Bgh + k0);
    *(int4*)&sBh[arow * LDA + aofs + 8] = *(const int4*)(Bgh + k0 + 8);
    *(int4*)&sBl[arow * LDA + aofs] = *(const int4*)(Bgl + k0);
    *(int4*)&sBl[arow * LDA + aofs + 8] = *(const int4*)(Bgl + k0 + 8);
    __syncthreads();

    short8 ah[4], al[4], bh[4], bl[4];
#pragma unroll
    for (int i = 0; i < 4; ++i) {
      int ar = (wm * 64 + i * 16 + mrow) * LDA + q * 8;
      int br = (wn * 64 + i * 16 + mrow) * LDA + q * 8;
      ah[i] = *(short8*)&sAh[ar];
      al[i] = *(short8*)&sAl[ar];
      bh[i] = *(short8*)&sBh[br];
      bl[i] = *(short8*)&sBl[br];
    }
#pragma unroll
    for (int i = 0; i < 4; ++i)
#pragma unroll
      for (int j = 0; j < 4; ++j) {
        acc[i][j] = __builtin_amdgcn_mfma_f32_16x16x32_bf16(ah[i], bh[j], acc[i][j], 0, 0, 0);
        acc[i][j] = __builtin_amdgcn_mfma_f32_16x16x32_bf16(ah[i], bl[j], acc[i][j], 0, 0, 0);
        acc[i][j] = __builtin_amdgcn_mfma_f32_16x16x32_bf16(al[i], bh[j], acc[i][j], 0, 0, 0);
      }
  }

  // ---- fused att: wave wn owns head hd's full 64-col stripe ----
  int hd = (c0 >> 6) + wn;
  float aS[4], aD[4];
#pragma unroll
  for (int j = 0; j < 4; ++j) {
    aS[j] = att_src[hd * 64 + j * 16 + mrow];
    aD[j] = att_dst[hd * 64 + j * 16 + mrow];
  }
#pragma unroll
  for (int i = 0; i < 4; ++i) {
#pragma unroll
    for (int r = 0; r < 4; ++r) {
      float ps = acc[i][0][r] * aS[0] + acc[i][1][r] * aS[1] +
                 acc[i][2][r] * aS[2] + acc[i][3][r] * aS[3];
      float pd = acc[i][0][r] * aD[0] + acc[i][1][r] * aD[1] +
                 acc[i][2][r] * aD[2] + acc[i][3][r] * aD[3];
#pragma unroll
      for (int o = 1; o < 16; o <<= 1) {
        ps += __shfl_xor(ps, o, 64);
        pd += __shfl_xor(pd, o, 64);
      }
      int grow = r0 + wm * 64 + i * 16 + q * 4 + r;
      if (mrow == 0 && grow < M) {
        asrc_o[grow * HEADS + hd] = ps;
        adst_o[grow * HEADS + hd] = pd;
      }
    }
  }

  // ---- bf16 C store (C/D layout: col=lane&15, row=(lane>>4)*4+reg) ----
#pragma unroll
  for (int i = 0; i < 4; ++i) {
#pragma unroll
    for (int j = 0; j < 4; ++j) {
      int col = c0 + wn * 64 + j * 16 + mrow;
#pragma unroll
      for (int r = 0; r < 4; ++r) {
        int grow = r0 + wm * 64 + i * 16 + q * 4 + r;
        if (grow < M) Cb[(size_t)grow * HC + col] = f2bf(acc[i][j][r]);
      }
    }
  }
}

__device__ __forceinline__ float lrelu(float x) { return x > 0.f ? x : NEG_SLOPE * x; }

// ---------------- segment softmax + aggregation: ONE WAVE PER NODE ----------------
// hproj is bf16 (512B/row) -> half the random-gather traffic.
__global__ __launch_bounds__(256) void aggregate_kernel(
    const unsigned short* __restrict__ hbf, const float* __restrict__ asrc,
    const float* __restrict__ adst, const int* __restrict__ row_ptr,
    const int* __restrict__ srcs, const float* __restrict__ bias,
    float* __restrict__ hout, int N) {
  __shared__ float s_alpha[4][64 * 4];
  __shared__ int s_src[4][64];

  int wave = threadIdx.x >> 6;
  int lane = threadIdx.x & 63;
  int node = blockIdx.x * 4 + wave;
  if (node >= N) return;

  int begin = row_ptr[node];
  int end = row_ptr[node + 1];
  int deg = end - begin;
  int nb = deg < 64 ? deg : 64;

  const float4* asrc4 = (const float4*)asrc;
  float4 ad = ((const float4*)adst)[node];

  const float NEGINF = -3.402823466e38f;
  int s0 = 0;
  float4 e0 = make_float4(NEGINF, NEGINF, NEGINF, NEGINF);
  if (lane < nb) {
    s0 = srcs[begin + lane];
    float4 a = asrc4[s0];
    e0.x = lrelu(a.x + ad.x);
    e0.y = lrelu(a.y + ad.y);
    e0.z = lrelu(a.z + ad.z);
    e0.w = lrelu(a.w + ad.w);
  }
  float m0 = e0.x, m1 = e0.y, m2 = e0.z, m3 = e0.w;
  for (int base = 64; base < deg; base += 64) {
    int idx = base + lane;
    if (idx < deg) {
      int s = srcs[begin + idx];
      float4 a = asrc4[s];
      m0 = fmaxf(m0, lrelu(a.x + ad.x));
      m1 = fmaxf(m1, lrelu(a.y + ad.y));
      m2 = fmaxf(m2, lrelu(a.z + ad.z));
      m3 = fmaxf(m3, lrelu(a.w + ad.w));
    }
  }
#pragma unroll
  for (int o = 1; o < 64; o <<= 1) {
    m0 = fmaxf(m0, __shfl_xor(m0, o, 64));
    m1 = fmaxf(m1, __shfl_xor(m1, o, 64));
    m2 = fmaxf(m2, __shfl_xor(m2, o, 64));
    m3 = fmaxf(m3, __shfl_xor(m3, o, 64));
  }
  float ex0 = (lane < nb) ? __expf(e0.x - m0) : 0.f;
  float ex1 = (lane < nb) ? __expf(e0.y - m1) : 0.f;
  float ex2 = (lane < nb) ? __expf(e0.z - m2) : 0.f;
  float ex3 = (lane < nb) ? __expf(e0.w - m3) : 0.f;
  float d0 = ex0, d1 = ex1, d2 = ex2, d3 = ex3;
  for (int base = 64; base < deg; base += 64) {
    int idx = base + lane;
    if (idx < deg) {
      int s = srcs[begin + idx];
      float4 a = asrc4[s];
      d0 += __expf(lrelu(a.x + ad.x) - m0);
      d1 += __expf(lrelu(a.y + ad.y) - m1);
      d2 += __expf(lrelu(a.z + ad.z) - m2);
      d3 += __expf(lrelu(a.w + ad.w) - m3);
    }
  }
#pragma unroll
  for (int o = 1; o < 64; o <<= 1) {
    d0 += __shfl_xor(d0, o, 64);
    d1 += __shfl_xor(d1, o, 64);
    d2 += __shfl_xor(d2, o, 64);
    d3 += __shfl_xor(d3, o, 64);
  }
  float r0 = 1.0f / (d0 + 1e-16f);
  float r1 = 1.0f / (d1 + 1e-16f);
  float r2 = 1.0f / (d2 + 1e-16f);
  float r3 = 1.0f / (d3 + 1e-16f);

  *(float4*)&s_alpha[wave][lane * 4] = make_float4(ex0 * r0, ex1 * r1, ex2 * r2, ex3 * r3);
  s_src[wave][lane] = s0;

  int head = lane >> 4;
  float mh = (head == 0) ? m0 : (head == 1) ? m1 : (head == 2) ? m2 : m3;
  float rdh = (head == 0) ? r0 : (head == 1) ? r1 : (head == 2) ? r2 : r3;
  float adh = (head == 0) ? ad.x : (head == 1) ? ad.y : (head == 2) ? ad.z : ad.w;

  const ushort4* hb4 = (const ushort4*)hbf;
  float4 accA = make_float4(0.f, 0.f, 0.f, 0.f);
  float4 accB = accA, accC = accA, accD = accA;
  int i = 0;
  for (; i + 4 <= nb; i += 4) {
    int sa = s_src[wave][i];
    int sb = s_src[wave][i + 1];
    int sc = s_src[wave][i + 2];
    int sd = s_src[wave][i + 3];
    float aa = s_alpha[wave][i * 4 + head];
    float ab = s_alpha[wave][(i + 1) * 4 + head];
    float ac = s_alpha[wave][(i + 2) * 4 + head];
    float ad_ = s_alpha[wave][(i + 3) * 4 + head];
    ushort4 u0 = hb4[(size_t)sa * 64 + lane];
    ushort4 u1 = hb4[(size_t)sb * 64 + lane];
    ushort4 u2 = hb4[(size_t)sc * 64 + lane];
    ushort4 u3 = hb4[(size_t)sd * 64 + lane];
    accA.x += aa * bf2f(u0.x); accA.y += aa * bf2f(u0.y);
    accA.z += aa * bf2f(u0.z); accA.w += aa * bf2f(u0.w);
    accB.x += ab * bf2f(u1.x); accB.y += ab * bf2f(u1.y);
    accB.z += ab * bf2f(u1.z); accB.w += ab * bf2f(u1.w);
    accC.x += ac * bf2f(u2.x); accC.y += ac * bf2f(u2.y);
    accC.z += ac * bf2f(u2.z); accC.w += ac * bf2f(u2.w);
    accD.x += ad_ * bf2f(u3.x); accD.y += ad_ * bf2f(u3.y);
    accD.z += ad_ * bf2f(u3.z); accD.w += ad_ * bf2f(u3.w);
  }
  for (; i < nb; ++i) {
    int s = s_src[wave][i];
    float a = s_alpha[wave][i * 4 + head];
    ushort4 u = hb4[(size_t)s * 64 + lane];
    accA.x += a * bf2f(u.x); accA.y += a * bf2f(u.y);
    accA.z += a * bf2f(u.z); accA.w += a * bf2f(u.w);
  }
  for (int i2 = 64; i2 < deg; ++i2) {
    int s = srcs[begin + i2];
    float ash = asrc[s * HEADS + head];
    float a = __expf(lrelu(ash + adh) - mh) * rdh;
    ushort4 u = hb4[(size_t)s * 64 + lane];
    accA.x += a * bf2f(u.x); accA.y += a * bf2f(u.y);
    accA.z += a * bf2f(u.z); accA.w += a * bf2f(u.w);
  }

  float4 acc;
  acc.x = (accA.x + accB.x) + (accC.x + accD.x);
  acc.y = (accA.y + accB.y) + (accC.y + accD.y);
  acc.z = (accA.z + accB.z) + (accC.z + accD.z);
  acc.w = (accA.w + accB.w) + (accC.w + accD.w);
  float4 bv = ((const float4*)bias)[lane];
  float4 o;
  o.x = fmaxf(acc.x + bv.x, 0.f);
  o.y = fmaxf(acc.y + bv.y, 0.f);
  o.z = fmaxf(acc.z + bv.z, 0.f);
  o.w = fmaxf(acc.w + bv.w, 0.f);
  ((float4*)hout)[(size_t)node * 64 + lane] = o;
}

// ---------------- global mean pool (batch is sorted) ----------------
__device__ __forceinline__ int lower_bound_i(const int* a, int n, int key) {
  int lo = 0, hi = n;
  while (lo < hi) {
    int mid = (lo + hi) >> 1;
    if (a[mid] < key) lo = mid + 1; else hi = mid;
  }
  return lo;
}

__global__ __launch_bounds__(256) void pool_kernel(const float* __restrict__ h2,
                                                   const int* __restrict__ batch,
                                                   float* __restrict__ pooled, int n) {
  int g = blockIdx.x;
  int wave = threadIdx.x >> 6, lane = threadIdx.x & 63;
  int lo = lower_bound_i(batch, n, g);
  int hi = lower_bound_i(batch, n, g + 1);
  const float4* h4 = (const float4*)h2;
  float4 acc = make_float4(0.f, 0.f, 0.f, 0.f);
  for (int i = lo + wave; i < hi; i += 4) {
    float4 v = h4[(size_t)i * 64 + lane];
    acc.x += v.x; acc.y += v.y; acc.z += v.z; acc.w += v.w;
  }
  __shared__ float4 red[4][64];
  red[wave][lane] = acc;
  __syncthreads();
  if (wave == 0) {
    float4 a0 = red[0][lane], a1 = red[1][lane], a2 = red[2][lane], a3 = red[3][lane];
    float inv = 1.0f / fmaxf((float)(hi - lo), 1.0f);
    float4 o;
    o.x = (a0.x + a1.x + a2.x + a3.x) * inv;
    o.y = (a0.y + a1.y + a2.y + a3.y) * inv;
    o.z = (a0.z + a1.z + a2.z + a3.z) * inv;
    o.w = (a0.w + a1.w + a2.w + a3.w) * inv;
    ((float4*)pooled)[g * 64 + lane] = o;
  }
}

// ---------------- final linear [G,256]@[256,10] ----------------
__global__ void final_kernel(const float* __restrict__ pooled, const float* __restrict__ Wf,
                             const float* __restrict__ bf, float* __restrict__ out) {
  int g = blockIdx.x, t = threadIdx.x;
  __shared__ float p[HC];
  p[t] = pooled[g * HC + t];
  __syncthreads();
  if (t < 10) {
    float s = bf[t];
    for (int c = 0; c < HC; ++c) s += p[c] * Wf[c * 10 + t];
    out[g * 10 + t] = s;
  }
}

extern "C" void kernel_launch(void* const* d_in, const int* in_sizes, int n_in,
                              void* d_out, int out_size, void* d_ws, size_t ws_size,
                              hipStream_t stream) {
  const float* x    = (const float*)d_in[0];
  const int*   ei   = (const int*)d_in[1];
  const int*   batch = (const int*)d_in[3];
  const float* W1   = (const float*)d_in[4];
  const float* as1  = (const float*)d_in[5];
  const float* ad1  = (const float*)d_in[6];
  const float* b1   = (const float*)d_in[7];
  const float* W2   = (const float*)d_in[8];
  const float* as2  = (const float*)d_in[9];
  const float* ad2  = (const float*)d_in[10];
  const float* b2   = (const float*)d_in[11];
  const float* Wf   = (const float*)d_in[12];
  const float* bf   = (const float*)d_in[13];
  float* out = (float*)d_out;

  const int N = in_sizes[0] / HC;  // 50000
  const int E = in_sizes[1] / 2;   // 800000

  // workspace layout
  float* bufB = (float*)d_ws;                         // N*256 fp32 (agg out / next GEMM A)
  unsigned short* hbf = (unsigned short*)(bufB + (size_t)N * HC);  // N*256 bf16
  float* asrc = (float*)(hbf + (size_t)N * HC);       // N*4
  float* adst = asrc + (size_t)N * HEADS;             // N*4
  int* counts = (int*)(adst + (size_t)N * HEADS);     // N
  int* row_ptr = counts + N;                          // N+1
  int* cursor = row_ptr + N + 1;                      // N
  int* srcs = cursor + N;                             // E+N
  unsigned short* Bth = (unsigned short*)(srcs + E + N);  // 256*256
  unsigned short* Btl = Bth + HC * HC;                    // 256*256

  // CSR build
  fill_counts_kernel<<<(N + 255) / 256, 256, 0, stream>>>(counts, N);
  hist_kernel<<<(E + 255) / 256, 256, 0, stream>>>(ei, counts, E);
  scan_kernel<<<1, 256, 0, stream>>>(counts, row_ptr, cursor, N);
  scatter_kernel<<<(E + N + 255) / 256, 256, 0, stream>>>(ei, cursor, srcs, E, N);

  dim3 ggrid(2, (N + 127) / 128);
  int agg_blocks = (N + 3) / 4;

  // layer 1
  convertB_kernel<<<HC, HC, 0, stream>>>(W1, Bth, Btl);
  gemm_kernel<<<ggrid, 256, 0, stream>>>(x, Bth, Btl, as1, ad1, hbf, asrc, adst, N);
  aggregate_kernel<<<agg_blocks, 256, 0, stream>>>(hbf, asrc, adst, row_ptr, srcs, b1, bufB, N);

  // layer 2
  convertB_kernel<<<HC, HC, 0, stream>>>(W2, Bth, Btl);
  gemm_kernel<<<ggrid, 256, 0, stream>>>(bufB, Bth, Btl, as2, ad2, hbf, asrc, adst, N);
  aggregate_kernel<<<agg_blocks, 256, 0, stream>>>(hbf, asrc, adst, row_ptr, srcs, b2, bufB, N);

  // pooling + classifier
  pool_kernel<<<GG, 256, 0, stream>>>(bufB, batch, out + GG * 10, N);
  final_kernel<<<GG, 256, 0, stream>>>(out + GG * 10, Wf, bf, out);
}

// Round 5
// 495.362 us; speedup vs baseline: 2.3864x; 1.1881x over previous
//
#include <hip/hip_runtime.h>
#include <math.h>

#define HEADS 4
#define HID 64
#define HC 256
#define NEG_SLOPE 0.2f
#define GG 128

typedef __attribute__((ext_vector_type(8))) short short8;
typedef __attribute__((ext_vector_type(4))) float floatx4;

__device__ __forceinline__ unsigned short f2bf(float f) {
  unsigned u = __float_as_uint(f);
  unsigned r = (u + 0x7FFFu + ((u >> 16) & 1u)) >> 16;  // RNE
  return (unsigned short)r;
}
__device__ __forceinline__ float bf2f(unsigned short h) {
  return __uint_as_float(((unsigned)h) << 16);
}

// ---------------- CSR build (counting sort by dst) ----------------
__global__ void fill_counts_kernel(int* counts, int n) {
  int i = blockIdx.x * 256 + threadIdx.x;
  if (i < n) counts[i] = 1;  // self loop
}

__global__ void hist_kernel(const int* __restrict__ ei, int* counts, int E) {
  int e = blockIdx.x * 256 + threadIdx.x;
  if (e < E) atomicAdd(&counts[ei[E + e]], 1);
}

// ---- 3-phase multi-block exclusive scan (1024 elements per block) ----
__global__ __launch_bounds__(256) void scan_pass1(const int* __restrict__ counts,
                                                  int* __restrict__ bsums, int n) {
  int t = threadIdx.x;
  int i0 = blockIdx.x * 1024 + t * 4;
  int s = 0;
  if (i0 + 3 < n) {
    int4 v = *(const int4*)&counts[i0];
    s = v.x + v.y + v.z + v.w;
  } else {
#pragma unroll
    for (int k = 0; k < 4; ++k)
      if (i0 + k < n) s += counts[i0 + k];
  }
#pragma unroll
  for (int o = 1; o < 64; o <<= 1) s += __shfl_xor(s, o, 64);
  __shared__ int ws[4];
  if ((t & 63) == 0) ws[t >> 6] = s;
  __syncthreads();
  if (t == 0) bsums[blockIdx.x] = ws[0] + ws[1] + ws[2] + ws[3];
}

__global__ __launch_bounds__(256) void scan_pass2(int* __restrict__ bsums,
                                                  int* __restrict__ row_ptr, int nb, int n) {
  __shared__ int sh[256];
  int t = threadIdx.x;
  int v = (t < nb) ? bsums[t] : 0;
  sh[t] = v;
  __syncthreads();
  for (int off = 1; off < 256; off <<= 1) {
    int u = (t >= off) ? sh[t - off] : 0;
    __syncthreads();
    sh[t] += u;
    __syncthreads();
  }
  if (t < nb) bsums[t] = sh[t] - v;  // exclusive
  if (t == 255) row_ptr[n] = sh[255];
}

__global__ __launch_bounds__(256) void scan_pass3(const int* __restrict__ counts,
                                                  const int* __restrict__ bsums,
                                                  int* __restrict__ row_ptr,
                                                  int* __restrict__ cursor, int n) {
  int t = threadIdx.x;
  int i0 = blockIdx.x * 1024 + t * 4;
  int c0 = 0, c1 = 0, c2 = 0, c3 = 0;
  bool full = (i0 + 3 < n);
  if (full) {
    int4 v = *(const int4*)&counts[i0];
    c0 = v.x; c1 = v.y; c2 = v.z; c3 = v.w;
  } else {
    if (i0 + 0 < n) c0 = counts[i0 + 0];
    if (i0 + 1 < n) c1 = counts[i0 + 1];
    if (i0 + 2 < n) c2 = counts[i0 + 2];
    if (i0 + 3 < n) c3 = counts[i0 + 3];
  }
  int ts = c0 + c1 + c2 + c3;
  __shared__ int sh[256];
  sh[t] = ts;
  __syncthreads();
  for (int off = 1; off < 256; off <<= 1) {
    int u = (t >= off) ? sh[t - off] : 0;
    __syncthreads();
    sh[t] += u;
    __syncthreads();
  }
  int run = bsums[blockIdx.x] + sh[t] - ts;
  int r0 = run, r1 = run + c0, r2 = r1 + c1, r3 = r2 + c2;
  if (full) {
    *(int4*)&row_ptr[i0] = make_int4(r0, r1, r2, r3);
    *(int4*)&cursor[i0] = make_int4(r0, r1, r2, r3);
  } else {
    if (i0 + 0 < n) { row_ptr[i0 + 0] = r0; cursor[i0 + 0] = r0; }
    if (i0 + 1 < n) { row_ptr[i0 + 1] = r1; cursor[i0 + 1] = r1; }
    if (i0 + 2 < n) { row_ptr[i0 + 2] = r2; cursor[i0 + 2] = r2; }
    if (i0 + 3 < n) { row_ptr[i0 + 3] = r3; cursor[i0 + 3] = r3; }
  }
}

__global__ void scatter_kernel(const int* __restrict__ ei, int* cursor, int* srcs, int E, int n) {
  int i = blockIdx.x * 256 + threadIdx.x;
  if (i >= E + n) return;
  int s, d;
  if (i < E) { s = ei[i]; d = ei[E + i]; }
  else       { s = i - E; d = s; }
  int pos = atomicAdd(&cursor[d], 1);
  srcs[pos] = s;
}

// ---------------- B pre-convert: fp32 [256,256] -> bf16 hi/lo TRANSPOSED [n][k] ----------------
__global__ void convertB_kernel(const float* __restrict__ B, unsigned short* __restrict__ Bth,
                                unsigned short* __restrict__ Btl) {
  int k = blockIdx.x, n = threadIdx.x;
  float v = B[k * HC + n];
  unsigned short h = f2bf(v);
  unsigned short l = f2bf(v - bf2f(h));
  Bth[n * HC + k] = h;
  Btl[n * HC + k] = l;
}

// ---------------- bf16-split MFMA GEMM + fused att + bf16 C ----------------
#define LDA 40  // padded k-stride in shorts (80B, 16B aligned)
__global__ __launch_bounds__(256) void gemm_kernel(
    const float* __restrict__ A, const unsigned short* __restrict__ Bth,
    const unsigned short* __restrict__ Btl, const float* __restrict__ att_src,
    const float* __restrict__ att_dst, unsigned short* __restrict__ Cb,
    float* __restrict__ asrc_o, float* __restrict__ adst_o, int M) {
  __shared__ unsigned short sAh[128 * LDA];
  __shared__ unsigned short sAl[128 * LDA];
  __shared__ unsigned short sBh[128 * LDA];
  __shared__ unsigned short sBl[128 * LDA];

  int t = threadIdx.x;
  int lane = t & 63, wave = t >> 6;
  int wm = wave >> 1, wn = wave & 1;
  int q = lane >> 4, mrow = lane & 15;
  int r0 = blockIdx.y * 128;
  int c0 = blockIdx.x * 128;

  int arow = t >> 1;
  int aofs = (t & 1) * 16;
  bool avalid = (r0 + arow) < M;
  const float* Ag = A + (size_t)(r0 + arow) * HC + aofs;
  const unsigned short* Bgh = Bth + (size_t)(c0 + arow) * HC + aofs;
  const unsigned short* Bgl = Btl + (size_t)(c0 + arow) * HC + aofs;

  floatx4 acc[4][4];
#pragma unroll
  for (int i = 0; i < 4; ++i)
#pragma unroll
    for (int j = 0; j < 4; ++j) acc[i][j] = (floatx4)(0.0f);

  for (int k0 = 0; k0 < HC; k0 += 32) {
    __syncthreads();
#pragma unroll
    for (int c = 0; c < 16; c += 4) {
      float4 v = make_float4(0.f, 0.f, 0.f, 0.f);
      if (avalid) v = *(const float4*)(Ag + k0 + c);
      unsigned short h0 = f2bf(v.x), h1 = f2bf(v.y), h2 = f2bf(v.z), h3 = f2bf(v.w);
      ushort4 hv = make_ushort4(h0, h1, h2, h3);
      ushort4 lv = make_ushort4(f2bf(v.x - bf2f(h0)), f2bf(v.y - bf2f(h1)),
                                f2bf(v.z - bf2f(h2)), f2bf(v.w - bf2f(h3)));
      *(ushort4*)&sAh[arow * LDA + aofs + c] = hv;
      *(ushort4*)&sAl[arow * LDA + aofs + c] = lv;
    }
    *(int4*)&sBh[arow * LDA + aofs] = *(const int4*)(Bgh + k0);
    *(int4*)&sBh[arow * LDA + aofs + 8] = *(const int4*)(Bgh + k0 + 8);
    *(int4*)&sBl[arow * LDA + aofs] = *(const int4*)(Bgl + k0);
    *(int4*)&sBl[arow * LDA + aofs + 8] = *(const int4*)(Bgl + k0 + 8);
    __syncthreads();

    short8 ah[4], al[4], bh[4], bl[4];
#pragma unroll
    for (int i = 0; i < 4; ++i) {
      int ar = (wm * 64 + i * 16 + mrow) * LDA + q * 8;
      int br = (wn * 64 + i * 16 + mrow) * LDA + q * 8;
      ah[i] = *(short8*)&sAh[ar];
      al[i] = *(short8*)&sAl[ar];
      bh[i] = *(short8*)&sBh[br];
      bl[i] = *(short8*)&sBl[br];
    }
#pragma unroll
    for (int i = 0; i < 4; ++i)
#pragma unroll
      for (int j = 0; j < 4; ++j) {
        acc[i][j] = __builtin_amdgcn_mfma_f32_16x16x32_bf16(ah[i], bh[j], acc[i][j], 0, 0, 0);
        acc[i][j] = __builtin_amdgcn_mfma_f32_16x16x32_bf16(ah[i], bl[j], acc[i][j], 0, 0, 0);
        acc[i][j] = __builtin_amdgcn_mfma_f32_16x16x32_bf16(al[i], bh[j], acc[i][j], 0, 0, 0);
      }
  }

  // ---- fused att: wave wn owns head hd's full 64-col stripe ----
  int hd = (c0 >> 6) + wn;
  float aS[4], aD[4];
#pragma unroll
  for (int j = 0; j < 4; ++j) {
    aS[j] = att_src[hd * 64 + j * 16 + mrow];
    aD[j] = att_dst[hd * 64 + j * 16 + mrow];
  }
#pragma unroll
  for (int i = 0; i < 4; ++i) {
#pragma unroll
    for (int r = 0; r < 4; ++r) {
      float ps = acc[i][0][r] * aS[0] + acc[i][1][r] * aS[1] +
                 acc[i][2][r] * aS[2] + acc[i][3][r] * aS[3];
      float pd = acc[i][0][r] * aD[0] + acc[i][1][r] * aD[1] +
                 acc[i][2][r] * aD[2] + acc[i][3][r] * aD[3];
#pragma unroll
      for (int o = 1; o < 16; o <<= 1) {
        ps += __shfl_xor(ps, o, 64);
        pd += __shfl_xor(pd, o, 64);
      }
      int grow = r0 + wm * 64 + i * 16 + q * 4 + r;
      if (mrow == 0 && grow < M) {
        asrc_o[grow * HEADS + hd] = ps;
        adst_o[grow * HEADS + hd] = pd;
      }
    }
  }

  // ---- bf16 C store (C/D layout: col=lane&15, row=(lane>>4)*4+reg) ----
#pragma unroll
  for (int i = 0; i < 4; ++i) {
#pragma unroll
    for (int j = 0; j < 4; ++j) {
      int col = c0 + wn * 64 + j * 16 + mrow;
#pragma unroll
      for (int r = 0; r < 4; ++r) {
        int grow = r0 + wm * 64 + i * 16 + q * 4 + r;
        if (grow < M) Cb[(size_t)grow * HC + col] = f2bf(acc[i][j][r]);
      }
    }
  }
}

__device__ __forceinline__ float lrelu(float x) { return x > 0.f ? x : NEG_SLOPE * x; }

// ---------------- segment softmax + aggregation: ONE WAVE PER NODE ----------------
__global__ __launch_bounds__(256) void aggregate_kernel(
    const unsigned short* __restrict__ hbf, const float* __restrict__ asrc,
    const float* __restrict__ adst, const int* __restrict__ row_ptr,
    const int* __restrict__ srcs, const float* __restrict__ bias,
    float* __restrict__ hout, int N) {
  __shared__ float s_alpha[4][64 * 4];
  __shared__ int s_src[4][64];

  int wave = threadIdx.x >> 6;
  int lane = threadIdx.x & 63;
  int node = blockIdx.x * 4 + wave;
  if (node >= N) return;

  int begin = row_ptr[node];
  int end = row_ptr[node + 1];
  int deg = end - begin;
  int nb = deg < 64 ? deg : 64;

  const float4* asrc4 = (const float4*)asrc;
  float4 ad = ((const float4*)adst)[node];

  const float NEGINF = -3.402823466e38f;
  int s0 = 0;
  float4 e0 = make_float4(NEGINF, NEGINF, NEGINF, NEGINF);
  if (lane < nb) {
    s0 = srcs[begin + lane];
    float4 a = asrc4[s0];
    e0.x = lrelu(a.x + ad.x);
    e0.y = lrelu(a.y + ad.y);
    e0.z = lrelu(a.z + ad.z);
    e0.w = lrelu(a.w + ad.w);
  }
  float m0 = e0.x, m1 = e0.y, m2 = e0.z, m3 = e0.w;
  for (int base = 64; base < deg; base += 64) {
    int idx = base + lane;
    if (idx < deg) {
      int s = srcs[begin + idx];
      float4 a = asrc4[s];
      m0 = fmaxf(m0, lrelu(a.x + ad.x));
      m1 = fmaxf(m1, lrelu(a.y + ad.y));
      m2 = fmaxf(m2, lrelu(a.z + ad.z));
      m3 = fmaxf(m3, lrelu(a.w + ad.w));
    }
  }
#pragma unroll
  for (int o = 1; o < 64; o <<= 1) {
    m0 = fmaxf(m0, __shfl_xor(m0, o, 64));
    m1 = fmaxf(m1, __shfl_xor(m1, o, 64));
    m2 = fmaxf(m2, __shfl_xor(m2, o, 64));
    m3 = fmaxf(m3, __shfl_xor(m3, o, 64));
  }
  float ex0 = (lane < nb) ? __expf(e0.x - m0) : 0.f;
  float ex1 = (lane < nb) ? __expf(e0.y - m1) : 0.f;
  float ex2 = (lane < nb) ? __expf(e0.z - m2) : 0.f;
  float ex3 = (lane < nb) ? __expf(e0.w - m3) : 0.f;
  float d0 = ex0, d1 = ex1, d2 = ex2, d3 = ex3;
  for (int base = 64; base < deg; base += 64) {
    int idx = base + lane;
    if (idx < deg) {
      int s = srcs[begin + idx];
      float4 a = asrc4[s];
      d0 += __expf(lrelu(a.x + ad.x) - m0);
      d1 += __expf(lrelu(a.y + ad.y) - m1);
      d2 += __expf(lrelu(a.z + ad.z) - m2);
      d3 += __expf(lrelu(a.w + ad.w) - m3);
    }
  }
#pragma unroll
  for (int o = 1; o < 64; o <<= 1) {
    d0 += __shfl_xor(d0, o, 64);
    d1 += __shfl_xor(d1, o, 64);
    d2 += __shfl_xor(d2, o, 64);
    d3 += __shfl_xor(d3, o, 64);
  }
  float r0 = 1.0f / (d0 + 1e-16f);
  float r1 = 1.0f / (d1 + 1e-16f);
  float r2 = 1.0f / (d2 + 1e-16f);
  float r3 = 1.0f / (d3 + 1e-16f);

  *(float4*)&s_alpha[wave][lane * 4] = make_float4(ex0 * r0, ex1 * r1, ex2 * r2, ex3 * r3);
  s_src[wave][lane] = s0;

  int head = lane >> 4;
  float mh = (head == 0) ? m0 : (head == 1) ? m1 : (head == 2) ? m2 : m3;
  float rdh = (head == 0) ? r0 : (head == 1) ? r1 : (head == 2) ? r2 : r3;
  float adh = (head == 0) ? ad.x : (head == 1) ? ad.y : (head == 2) ? ad.z : ad.w;

  const ushort4* hb4 = (const ushort4*)hbf;
  float4 accA = make_float4(0.f, 0.f, 0.f, 0.f);
  float4 accB = accA, accC = accA, accD = accA;
  int i = 0;
  for (; i + 4 <= nb; i += 4) {
    int sa = s_src[wave][i];
    int sb = s_src[wave][i + 1];
    int sc = s_src[wave][i + 2];
    int sd = s_src[wave][i + 3];
    float aa = s_alpha[wave][i * 4 + head];
    float ab = s_alpha[wave][(i + 1) * 4 + head];
    float ac = s_alpha[wave][(i + 2) * 4 + head];
    float ad_ = s_alpha[wave][(i + 3) * 4 + head];
    ushort4 u0 = hb4[(size_t)sa * 64 + lane];
    ushort4 u1 = hb4[(size_t)sb * 64 + lane];
    ushort4 u2 = hb4[(size_t)sc * 64 + lane];
    ushort4 u3 = hb4[(size_t)sd * 64 + lane];
    accA.x += aa * bf2f(u0.x); accA.y += aa * bf2f(u0.y);
    accA.z += aa * bf2f(u0.z); accA.w += aa * bf2f(u0.w);
    accB.x += ab * bf2f(u1.x); accB.y += ab * bf2f(u1.y);
    accB.z += ab * bf2f(u1.z); accB.w += ab * bf2f(u1.w);
    accC.x += ac * bf2f(u2.x); accC.y += ac * bf2f(u2.y);
    accC.z += ac * bf2f(u2.z); accC.w += ac * bf2f(u2.w);
    accD.x += ad_ * bf2f(u3.x); accD.y += ad_ * bf2f(u3.y);
    accD.z += ad_ * bf2f(u3.z); accD.w += ad_ * bf2f(u3.w);
  }
  for (; i < nb; ++i) {
    int s = s_src[wave][i];
    float a = s_alpha[wave][i * 4 + head];
    ushort4 u = hb4[(size_t)s * 64 + lane];
    accA.x += a * bf2f(u.x); accA.y += a * bf2f(u.y);
    accA.z += a * bf2f(u.z); accA.w += a * bf2f(u.w);
  }
  for (int i2 = 64; i2 < deg; ++i2) {
    int s = srcs[begin + i2];
    float ash = asrc[s * HEADS + head];
    float a = __expf(lrelu(ash + adh) - mh) * rdh;
    ushort4 u = hb4[(size_t)s * 64 + lane];
    accA.x += a * bf2f(u.x); accA.y += a * bf2f(u.y);
    accA.z += a * bf2f(u.z); accA.w += a * bf2f(u.w);
  }

  float4 acc;
  acc.x = (accA.x + accB.x) + (accC.x + accD.x);
  acc.y = (accA.y + accB.y) + (accC.y + accD.y);
  acc.z = (accA.z + accB.z) + (accC.z + accD.z);
  acc.w = (accA.w + accB.w) + (accC.w + accD.w);
  float4 bv = ((const float4*)bias)[lane];
  float4 o;
  o.x = fmaxf(acc.x + bv.x, 0.f);
  o.y = fmaxf(acc.y + bv.y, 0.f);
  o.z = fmaxf(acc.z + bv.z, 0.f);
  o.w = fmaxf(acc.w + bv.w, 0.f);
  ((float4*)hout)[(size_t)node * 64 + lane] = o;
}

// ---------------- global mean pool (batch is sorted) ----------------
__device__ __forceinline__ int lower_bound_i(const int* a, int n, int key) {
  int lo = 0, hi = n;
  while (lo < hi) {
    int mid = (lo + hi) >> 1;
    if (a[mid] < key) lo = mid + 1; else hi = mid;
  }
  return lo;
}

__global__ __launch_bounds__(256) void pool_kernel(const float* __restrict__ h2,
                                                   const int* __restrict__ batch,
                                                   float* __restrict__ pooled, int n) {
  int g = blockIdx.x;
  int wave = threadIdx.x >> 6, lane = threadIdx.x & 63;
  int lo = lower_bound_i(batch, n, g);
  int hi = lower_bound_i(batch, n, g + 1);
  const float4* h4 = (const float4*)h2;
  float4 acc = make_float4(0.f, 0.f, 0.f, 0.f);
  for (int i = lo + wave; i < hi; i += 4) {
    float4 v = h4[(size_t)i * 64 + lane];
    acc.x += v.x; acc.y += v.y; acc.z += v.z; acc.w += v.w;
  }
  __shared__ float4 red[4][64];
  red[wave][lane] = acc;
  __syncthreads();
  if (wave == 0) {
    float4 a0 = red[0][lane], a1 = red[1][lane], a2 = red[2][lane], a3 = red[3][lane];
    float inv = 1.0f / fmaxf((float)(hi - lo), 1.0f);
    float4 o;
    o.x = (a0.x + a1.x + a2.x + a3.x) * inv;
    o.y = (a0.y + a1.y + a2.y + a3.y) * inv;
    o.z = (a0.z + a1.z + a2.z + a3.z) * inv;
    o.w = (a0.w + a1.w + a2.w + a3.w) * inv;
    ((float4*)pooled)[g * 64 + lane] = o;
  }
}

// ---------------- final linear [G,256]@[256,10] ----------------
__global__ void final_kernel(const float* __restrict__ pooled, const float* __restrict__ Wf,
                             const float* __restrict__ bf, float* __restrict__ out) {
  int g = blockIdx.x, t = threadIdx.x;
  __shared__ float p[HC];
  p[t] = pooled[g * HC + t];
  __syncthreads();
  if (t < 10) {
    float s = bf[t];
    for (int c = 0; c < HC; ++c) s += p[c] * Wf[c * 10 + t];
    out[g * 10 + t] = s;
  }
}

extern "C" void kernel_launch(void* const* d_in, const int* in_sizes, int n_in,
                              void* d_out, int out_size, void* d_ws, size_t ws_size,
                              hipStream_t stream) {
  const float* x    = (const float*)d_in[0];
  const int*   ei   = (const int*)d_in[1];
  const int*   batch = (const int*)d_in[3];
  const float* W1   = (const float*)d_in[4];
  const float* as1  = (const float*)d_in[5];
  const float* ad1  = (const float*)d_in[6];
  const float* b1   = (const float*)d_in[7];
  const float* W2   = (const float*)d_in[8];
  const float* as2  = (const float*)d_in[9];
  const float* ad2  = (const float*)d_in[10];
  const float* b2   = (const float*)d_in[11];
  const float* Wf   = (const float*)d_in[12];
  const float* bf   = (const float*)d_in[13];
  float* out = (float*)d_out;

  const int N = in_sizes[0] / HC;  // 50000
  const int E = in_sizes[1] / 2;   // 800000

  // workspace layout
  float* bufB = (float*)d_ws;                         // N*256 fp32 (agg out / next GEMM A)
  unsigned short* hbf = (unsigned short*)(bufB + (size_t)N * HC);  // N*256 bf16
  float* asrc = (float*)(hbf + (size_t)N * HC);       // N*4
  float* adst = asrc + (size_t)N * HEADS;             // N*4
  int* counts = (int*)(adst + (size_t)N * HEADS);     // N
  int* row_ptr = counts + N;                          // N+1
  int* cursor = row_ptr + N + 1;                      // N
  int* srcs = cursor + N;                             // E+N
  int* bsums = srcs + E + N;                          // ceil(N/1024)
  unsigned short* Bth = (unsigned short*)(bsums + ((N + 1023) / 1024 + 4));  // 256*256
  unsigned short* Btl = Bth + HC * HC;                                       // 256*256

  int nb = (N + 1023) / 1024;

  // CSR build
  fill_counts_kernel<<<(N + 255) / 256, 256, 0, stream>>>(counts, N);
  hist_kernel<<<(E + 255) / 256, 256, 0, stream>>>(ei, counts, E);
  scan_pass1<<<nb, 256, 0, stream>>>(counts, bsums, N);
  scan_pass2<<<1, 256, 0, stream>>>(bsums, row_ptr, nb, N);
  scan_pass3<<<nb, 256, 0, stream>>>(counts, bsums, row_ptr, cursor, N);
  scatter_kernel<<<(E + N + 255) / 256, 256, 0, stream>>>(ei, cursor, srcs, E, N);

  dim3 ggrid(2, (N + 127) / 128);
  int agg_blocks = (N + 3) / 4;

  // layer 1
  convertB_kernel<<<HC, HC, 0, stream>>>(W1, Bth, Btl);
  gemm_kernel<<<ggrid, 256, 0, stream>>>(x, Bth, Btl, as1, ad1, hbf, asrc, adst, N);
  aggregate_kernel<<<agg_blocks, 256, 0, stream>>>(hbf, asrc, adst, row_ptr, srcs, b1, bufB, N);

  // layer 2
  convertB_kernel<<<HC, HC, 0, stream>>>(W2, Bth, Btl);
  gemm_kernel<<<ggrid, 256, 0, stream>>>(bufB, Bth, Btl, as2, ad2, hbf, asrc, adst, N);
  aggregate_kernel<<<agg_blocks, 256, 0, stream>>>(hbf, asrc, adst, row_ptr, srcs, b2, bufB, N);

  // pooling + classifier
  pool_kernel<<<GG, 256, 0, stream>>>(bufB, batch, out + GG * 10, N);
  final_kernel<<<GG, 256, 0, stream>>>(out + GG * 10, Wf, bf, out);
}

// Round 6
// 482.280 us; speedup vs baseline: 2.4511x; 1.0271x over previous
//
#include <hip/hip_runtime.h>
#include <math.h>

#define HEADS 4
#define HID 64
#define HC 256
#define NEG_SLOPE 0.2f
#define GG 128

typedef __attribute__((ext_vector_type(8))) short short8;
typedef __attribute__((ext_vector_type(4))) float floatx4;
typedef unsigned short ush;

__device__ __forceinline__ ush f2bf(float f) {
  unsigned u = __float_as_uint(f);
  unsigned r = (u + 0x7FFFu + ((u >> 16) & 1u)) >> 16;  // RNE
  return (ush)r;
}
__device__ __forceinline__ float bf2f(ush h) {
  return __uint_as_float(((unsigned)h) << 16);
}

// ---------------- CSR build (counting sort by dst) ----------------
__global__ void fill_counts_kernel(int* counts, int n) {
  int i = blockIdx.x * 256 + threadIdx.x;
  if (i < n) counts[i] = 1;  // self loop
}

__global__ void hist_kernel(const int* __restrict__ ei, int* counts, int E) {
  int e = blockIdx.x * 256 + threadIdx.x;
  if (e < E) atomicAdd(&counts[ei[E + e]], 1);
}

__global__ __launch_bounds__(256) void scan_pass1(const int* __restrict__ counts,
                                                  int* __restrict__ bsums, int n) {
  int t = threadIdx.x;
  int i0 = blockIdx.x * 1024 + t * 4;
  int s = 0;
  if (i0 + 3 < n) {
    int4 v = *(const int4*)&counts[i0];
    s = v.x + v.y + v.z + v.w;
  } else {
#pragma unroll
    for (int k = 0; k < 4; ++k)
      if (i0 + k < n) s += counts[i0 + k];
  }
#pragma unroll
  for (int o = 1; o < 64; o <<= 1) s += __shfl_xor(s, o, 64);
  __shared__ int ws[4];
  if ((t & 63) == 0) ws[t >> 6] = s;
  __syncthreads();
  if (t == 0) bsums[blockIdx.x] = ws[0] + ws[1] + ws[2] + ws[3];
}

__global__ __launch_bounds__(256) void scan_pass2(int* __restrict__ bsums,
                                                  int* __restrict__ row_ptr, int nb, int n) {
  __shared__ int sh[256];
  int t = threadIdx.x;
  int v = (t < nb) ? bsums[t] : 0;
  sh[t] = v;
  __syncthreads();
  for (int off = 1; off < 256; off <<= 1) {
    int u = (t >= off) ? sh[t - off] : 0;
    __syncthreads();
    sh[t] += u;
    __syncthreads();
  }
  if (t < nb) bsums[t] = sh[t] - v;  // exclusive
  if (t == 255) row_ptr[n] = sh[255];
}

__global__ __launch_bounds__(256) void scan_pass3(const int* __restrict__ counts,
                                                  const int* __restrict__ bsums,
                                                  int* __restrict__ row_ptr,
                                                  int* __restrict__ cursor, int n) {
  int t = threadIdx.x;
  int i0 = blockIdx.x * 1024 + t * 4;
  int c0 = 0, c1 = 0, c2 = 0, c3 = 0;
  bool full = (i0 + 3 < n);
  if (full) {
    int4 v = *(const int4*)&counts[i0];
    c0 = v.x; c1 = v.y; c2 = v.z; c3 = v.w;
  } else {
    if (i0 + 0 < n) c0 = counts[i0 + 0];
    if (i0 + 1 < n) c1 = counts[i0 + 1];
    if (i0 + 2 < n) c2 = counts[i0 + 2];
    if (i0 + 3 < n) c3 = counts[i0 + 3];
  }
  int ts = c0 + c1 + c2 + c3;
  __shared__ int sh[256];
  sh[t] = ts;
  __syncthreads();
  for (int off = 1; off < 256; off <<= 1) {
    int u = (t >= off) ? sh[t - off] : 0;
    __syncthreads();
    sh[t] += u;
    __syncthreads();
  }
  int run = bsums[blockIdx.x] + sh[t] - ts;
  int r0 = run, r1 = run + c0, r2 = r1 + c1, r3 = r2 + c2;
  if (full) {
    *(int4*)&row_ptr[i0] = make_int4(r0, r1, r2, r3);
    *(int4*)&cursor[i0] = make_int4(r0, r1, r2, r3);
  } else {
    if (i0 + 0 < n) { row_ptr[i0 + 0] = r0; cursor[i0 + 0] = r0; }
    if (i0 + 1 < n) { row_ptr[i0 + 1] = r1; cursor[i0 + 1] = r1; }
    if (i0 + 2 < n) { row_ptr[i0 + 2] = r2; cursor[i0 + 2] = r2; }
    if (i0 + 3 < n) { row_ptr[i0 + 3] = r3; cursor[i0 + 3] = r3; }
  }
}

__global__ void scatter_kernel(const int* __restrict__ ei, int* cursor, int* srcs, int E, int n) {
  int i = blockIdx.x * 256 + threadIdx.x;
  if (i >= E + n) return;
  int s, d;
  if (i < E) { s = ei[i]; d = ei[E + i]; }
  else       { s = i - E; d = s; }
  int pos = atomicAdd(&cursor[d], 1);
  srcs[pos] = s;
}

// ---------------- fp32 -> bf16 hi/lo split (elementwise) ----------------
__global__ __launch_bounds__(256) void splitA_kernel(const float* __restrict__ A,
                                                     ush* __restrict__ Ah,
                                                     ush* __restrict__ Al, int total) {
  int i0 = (blockIdx.x * 256 + threadIdx.x) * 4;
  if (i0 + 3 < total) {
    float4 v = *(const float4*)&A[i0];
    ushort4 h = make_ushort4(f2bf(v.x), f2bf(v.y), f2bf(v.z), f2bf(v.w));
    ushort4 l = make_ushort4(f2bf(v.x - bf2f(h.x)), f2bf(v.y - bf2f(h.y)),
                             f2bf(v.z - bf2f(h.z)), f2bf(v.w - bf2f(h.w)));
    *(ushort4*)&Ah[i0] = h;
    *(ushort4*)&Al[i0] = l;
  } else {
    for (int k = 0; k < 4 && i0 + k < total; ++k) {
      float v = A[i0 + k];
      ush h = f2bf(v);
      Ah[i0 + k] = h;
      Al[i0 + k] = f2bf(v - bf2f(h));
    }
  }
}

// ---------------- B pre-convert: fp32 [256,256] -> bf16 hi/lo TRANSPOSED [n][k] ----------------
__global__ void convertB_kernel(const float* __restrict__ B, ush* __restrict__ Bth,
                                ush* __restrict__ Btl) {
  int k = blockIdx.x, n = threadIdx.x;
  float v = B[k * HC + n];
  ush h = f2bf(v);
  ush l = f2bf(v - bf2f(h));
  Bth[n * HC + k] = h;
  Btl[n * HC + k] = l;
}

// ---------------- bf16-split MFMA GEMM (pre-split A) + fused att + bf16 C ----------------
#define LDA 40  // padded k-stride in shorts (80B, 16B aligned)
__global__ __launch_bounds__(256) void gemm_kernel(
    const ush* __restrict__ Ah, const ush* __restrict__ Al,
    const ush* __restrict__ Bth, const ush* __restrict__ Btl,
    const float* __restrict__ att_src, const float* __restrict__ att_dst,
    ush* __restrict__ Cb, float* __restrict__ asrc_o, float* __restrict__ adst_o, int M) {
  __shared__ ush sAh[128 * LDA];
  __shared__ ush sAl[128 * LDA];
  __shared__ ush sBh[128 * LDA];
  __shared__ ush sBl[128 * LDA];

  int t = threadIdx.x;
  int lane = t & 63, wave = t >> 6;
  int wm = wave >> 1, wn = wave & 1;
  int q = lane >> 4, mrow = lane & 15;
  int r0 = blockIdx.y * 128;
  int c0 = blockIdx.x * 128;

  // staging tasks: 512 (row,seg) pairs per array; thread does task t and t+256
  int row0 = t >> 2, seg0 = t & 3;
  int row1 = (t + 256) >> 2, seg1 = (t + 256) & 3;
  bool v0 = (r0 + row0) < M, v1 = (r0 + row1) < M;
  const int4 zero4 = make_int4(0, 0, 0, 0);

  floatx4 acc[4][4];
#pragma unroll
  for (int i = 0; i < 4; ++i)
#pragma unroll
    for (int j = 0; j < 4; ++j) acc[i][j] = (floatx4)(0.0f);

  for (int k0 = 0; k0 < HC; k0 += 32) {
    __syncthreads();
    {
      size_t g0 = (size_t)(r0 + row0) * HC + k0 + seg0 * 8;
      size_t g1 = (size_t)(r0 + row1) * HC + k0 + seg1 * 8;
      *(int4*)&sAh[row0 * LDA + seg0 * 8] = v0 ? *(const int4*)&Ah[g0] : zero4;
      *(int4*)&sAh[row1 * LDA + seg1 * 8] = v1 ? *(const int4*)&Ah[g1] : zero4;
      *(int4*)&sAl[row0 * LDA + seg0 * 8] = v0 ? *(const int4*)&Al[g0] : zero4;
      *(int4*)&sAl[row1 * LDA + seg1 * 8] = v1 ? *(const int4*)&Al[g1] : zero4;
      size_t b0 = (size_t)(c0 + row0) * HC + k0 + seg0 * 8;
      size_t b1 = (size_t)(c0 + row1) * HC + k0 + seg1 * 8;
      *(int4*)&sBh[row0 * LDA + seg0 * 8] = *(const int4*)&Bth[b0];
      *(int4*)&sBh[row1 * LDA + seg1 * 8] = *(const int4*)&Bth[b1];
      *(int4*)&sBl[row0 * LDA + seg0 * 8] = *(const int4*)&Btl[b0];
      *(int4*)&sBl[row1 * LDA + seg1 * 8] = *(const int4*)&Btl[b1];
    }
    __syncthreads();

    short8 ah[4], al[4], bh[4], bl[4];
#pragma unroll
    for (int i = 0; i < 4; ++i) {
      int ar = (wm * 64 + i * 16 + mrow) * LDA + q * 8;
      int br = (wn * 64 + i * 16 + mrow) * LDA + q * 8;
      ah[i] = *(short8*)&sAh[ar];
      al[i] = *(short8*)&sAl[ar];
      bh[i] = *(short8*)&sBh[br];
      bl[i] = *(short8*)&sBl[br];
    }
#pragma unroll
    for (int i = 0; i < 4; ++i)
#pragma unroll
      for (int j = 0; j < 4; ++j) {
        acc[i][j] = __builtin_amdgcn_mfma_f32_16x16x32_bf16(ah[i], bh[j], acc[i][j], 0, 0, 0);
        acc[i][j] = __builtin_amdgcn_mfma_f32_16x16x32_bf16(ah[i], bl[j], acc[i][j], 0, 0, 0);
        acc[i][j] = __builtin_amdgcn_mfma_f32_16x16x32_bf16(al[i], bh[j], acc[i][j], 0, 0, 0);
      }
  }

  // ---- fused att: wave wn owns head hd's full 64-col stripe ----
  int hd = (c0 >> 6) + wn;
  float aS[4], aD[4];
#pragma unroll
  for (int j = 0; j < 4; ++j) {
    aS[j] = att_src[hd * 64 + j * 16 + mrow];
    aD[j] = att_dst[hd * 64 + j * 16 + mrow];
  }
#pragma unroll
  for (int i = 0; i < 4; ++i) {
#pragma unroll
    for (int r = 0; r < 4; ++r) {
      float ps = acc[i][0][r] * aS[0] + acc[i][1][r] * aS[1] +
                 acc[i][2][r] * aS[2] + acc[i][3][r] * aS[3];
      float pd = acc[i][0][r] * aD[0] + acc[i][1][r] * aD[1] +
                 acc[i][2][r] * aD[2] + acc[i][3][r] * aD[3];
#pragma unroll
      for (int o = 1; o < 16; o <<= 1) {
        ps += __shfl_xor(ps, o, 64);
        pd += __shfl_xor(pd, o, 64);
      }
      int grow = r0 + wm * 64 + i * 16 + q * 4 + r;
      if (mrow == 0 && grow < M) {
        asrc_o[grow * HEADS + hd] = ps;
        adst_o[grow * HEADS + hd] = pd;
      }
    }
  }

  // ---- bf16 C store (C/D layout: col=lane&15, row=(lane>>4)*4+reg) ----
#pragma unroll
  for (int i = 0; i < 4; ++i) {
#pragma unroll
    for (int j = 0; j < 4; ++j) {
      int col = c0 + wn * 64 + j * 16 + mrow;
#pragma unroll
      for (int r = 0; r < 4; ++r) {
        int grow = r0 + wm * 64 + i * 16 + q * 4 + r;
        if (grow < M) Cb[(size_t)grow * HC + col] = f2bf(acc[i][j][r]);
      }
    }
  }
}

__device__ __forceinline__ float lrelu(float x) { return x > 0.f ? x : NEG_SLOPE * x; }

// ---------------- segment softmax + aggregation: ONE WAVE PER NODE ----------------
// Output either fp32 (outf != null) or bf16 hi/lo split (outh/outl).
__global__ __launch_bounds__(256) void aggregate_kernel(
    const ush* __restrict__ hbf, const float* __restrict__ asrc,
    const float* __restrict__ adst, const int* __restrict__ row_ptr,
    const int* __restrict__ srcs, const float* __restrict__ bias,
    float* __restrict__ outf, ush* __restrict__ outh, ush* __restrict__ outl, int N) {
  __shared__ float s_alpha[4][64 * 4];
  __shared__ int s_src[4][64];

  int wave = threadIdx.x >> 6;
  int lane = threadIdx.x & 63;
  int node = blockIdx.x * 4 + wave;
  if (node >= N) return;

  int begin = row_ptr[node];
  int end = row_ptr[node + 1];
  int deg = end - begin;
  int nb = deg < 64 ? deg : 64;

  const float4* asrc4 = (const float4*)asrc;
  float4 ad = ((const float4*)adst)[node];

  const float NEGINF = -3.402823466e38f;
  int s0 = 0;
  float4 e0 = make_float4(NEGINF, NEGINF, NEGINF, NEGINF);
  if (lane < nb) {
    s0 = srcs[begin + lane];
    float4 a = asrc4[s0];
    e0.x = lrelu(a.x + ad.x);
    e0.y = lrelu(a.y + ad.y);
    e0.z = lrelu(a.z + ad.z);
    e0.w = lrelu(a.w + ad.w);
  }
  float m0 = e0.x, m1 = e0.y, m2 = e0.z, m3 = e0.w;
  for (int base = 64; base < deg; base += 64) {
    int idx = base + lane;
    if (idx < deg) {
      int s = srcs[begin + idx];
      float4 a = asrc4[s];
      m0 = fmaxf(m0, lrelu(a.x + ad.x));
      m1 = fmaxf(m1, lrelu(a.y + ad.y));
      m2 = fmaxf(m2, lrelu(a.z + ad.z));
      m3 = fmaxf(m3, lrelu(a.w + ad.w));
    }
  }
#pragma unroll
  for (int o = 1; o < 64; o <<= 1) {
    m0 = fmaxf(m0, __shfl_xor(m0, o, 64));
    m1 = fmaxf(m1, __shfl_xor(m1, o, 64));
    m2 = fmaxf(m2, __shfl_xor(m2, o, 64));
    m3 = fmaxf(m3, __shfl_xor(m3, o, 64));
  }
  float ex0 = (lane < nb) ? __expf(e0.x - m0) : 0.f;
  float ex1 = (lane < nb) ? __expf(e0.y - m1) : 0.f;
  float ex2 = (lane < nb) ? __expf(e0.z - m2) : 0.f;
  float ex3 = (lane < nb) ? __expf(e0.w - m3) : 0.f;
  float d0 = ex0, d1 = ex1, d2 = ex2, d3 = ex3;
  for (int base = 64; base < deg; base += 64) {
    int idx = base + lane;
    if (idx < deg) {
      int s = srcs[begin + idx];
      float4 a = asrc4[s];
      d0 += __expf(lrelu(a.x + ad.x) - m0);
      d1 += __expf(lrelu(a.y + ad.y) - m1);
      d2 += __expf(lrelu(a.z + ad.z) - m2);
      d3 += __expf(lrelu(a.w + ad.w) - m3);
    }
  }
#pragma unroll
  for (int o = 1; o < 64; o <<= 1) {
    d0 += __shfl_xor(d0, o, 64);
    d1 += __shfl_xor(d1, o, 64);
    d2 += __shfl_xor(d2, o, 64);
    d3 += __shfl_xor(d3, o, 64);
  }
  float r0 = 1.0f / (d0 + 1e-16f);
  float r1 = 1.0f / (d1 + 1e-16f);
  float r2 = 1.0f / (d2 + 1e-16f);
  float r3 = 1.0f / (d3 + 1e-16f);

  *(float4*)&s_alpha[wave][lane * 4] = make_float4(ex0 * r0, ex1 * r1, ex2 * r2, ex3 * r3);
  s_src[wave][lane] = s0;

  int head = lane >> 4;
  float mh = (head == 0) ? m0 : (head == 1) ? m1 : (head == 2) ? m2 : m3;
  float rdh = (head == 0) ? r0 : (head == 1) ? r1 : (head == 2) ? r2 : r3;
  float adh = (head == 0) ? ad.x : (head == 1) ? ad.y : (head == 2) ? ad.z : ad.w;

  const ushort4* hb4 = (const ushort4*)hbf;
  float4 accA = make_float4(0.f, 0.f, 0.f, 0.f);
  float4 accB = accA, accC = accA, accD = accA;
  int i = 0;
  for (; i + 4 <= nb; i += 4) {
    int sa = s_src[wave][i];
    int sb = s_src[wave][i + 1];
    int sc = s_src[wave][i + 2];
    int sd = s_src[wave][i + 3];
    float aa = s_alpha[wave][i * 4 + head];
    float ab = s_alpha[wave][(i + 1) * 4 + head];
    float ac = s_alpha[wave][(i + 2) * 4 + head];
    float ad_ = s_alpha[wave][(i + 3) * 4 + head];
    ushort4 u0 = hb4[(size_t)sa * 64 + lane];
    ushort4 u1 = hb4[(size_t)sb * 64 + lane];
    ushort4 u2 = hb4[(size_t)sc * 64 + lane];
    ushort4 u3 = hb4[(size_t)sd * 64 + lane];
    accA.x += aa * bf2f(u0.x); accA.y += aa * bf2f(u0.y);
    accA.z += aa * bf2f(u0.z); accA.w += aa * bf2f(u0.w);
    accB.x += ab * bf2f(u1.x); accB.y += ab * bf2f(u1.y);
    accB.z += ab * bf2f(u1.z); accB.w += ab * bf2f(u1.w);
    accC.x += ac * bf2f(u2.x); accC.y += ac * bf2f(u2.y);
    accC.z += ac * bf2f(u2.z); accC.w += ac * bf2f(u2.w);
    accD.x += ad_ * bf2f(u3.x); accD.y += ad_ * bf2f(u3.y);
    accD.z += ad_ * bf2f(u3.z); accD.w += ad_ * bf2f(u3.w);
  }
  for (; i < nb; ++i) {
    int s = s_src[wave][i];
    float a = s_alpha[wave][i * 4 + head];
    ushort4 u = hb4[(size_t)s * 64 + lane];
    accA.x += a * bf2f(u.x); accA.y += a * bf2f(u.y);
    accA.z += a * bf2f(u.z); accA.w += a * bf2f(u.w);
  }
  for (int i2 = 64; i2 < deg; ++i2) {
    int s = srcs[begin + i2];
    float ash = asrc[s * HEADS + head];
    float a = __expf(lrelu(ash + adh) - mh) * rdh;
    ushort4 u = hb4[(size_t)s * 64 + lane];
    accA.x += a * bf2f(u.x); accA.y += a * bf2f(u.y);
    accA.z += a * bf2f(u.z); accA.w += a * bf2f(u.w);
  }

  float4 acc;
  acc.x = (accA.x + accB.x) + (accC.x + accD.x);
  acc.y = (accA.y + accB.y) + (accC.y + accD.y);
  acc.z = (accA.z + accB.z) + (accC.z + accD.z);
  acc.w = (accA.w + accB.w) + (accC.w + accD.w);
  float4 bv = ((const float4*)bias)[lane];
  float4 o;
  o.x = fmaxf(acc.x + bv.x, 0.f);
  o.y = fmaxf(acc.y + bv.y, 0.f);
  o.z = fmaxf(acc.z + bv.z, 0.f);
  o.w = fmaxf(acc.w + bv.w, 0.f);

  if (outf) {
    ((float4*)outf)[(size_t)node * 64 + lane] = o;
  } else {
    ushort4 h = make_ushort4(f2bf(o.x), f2bf(o.y), f2bf(o.z), f2bf(o.w));
    ushort4 l = make_ushort4(f2bf(o.x - bf2f(h.x)), f2bf(o.y - bf2f(h.y)),
                             f2bf(o.z - bf2f(h.z)), f2bf(o.w - bf2f(h.w)));
    ((ushort4*)outh)[(size_t)node * 64 + lane] = h;
    ((ushort4*)outl)[(size_t)node * 64 + lane] = l;
  }
}

// ---------------- global mean pool (batch is sorted), 4 partials per graph ----------------
__device__ __forceinline__ int lower_bound_i(const int* a, int n, int key) {
  int lo = 0, hi = n;
  while (lo < hi) {
    int mid = (lo + hi) >> 1;
    if (a[mid] < key) lo = mid + 1; else hi = mid;
  }
  return lo;
}

__global__ __launch_bounds__(256) void pool_kernel(const float* __restrict__ h2,
                                                   const int* __restrict__ batch,
                                                   float* __restrict__ pws,
                                                   int* __restrict__ cnts, int n) {
  int g = blockIdx.x, part = blockIdx.y;
  int wave = threadIdx.x >> 6, lane = threadIdx.x & 63;
  int lo = lower_bound_i(batch, n, g);
  int hi = lower_bound_i(batch, n, g + 1);
  const float4* h4 = (const float4*)h2;
  float4 acc = make_float4(0.f, 0.f, 0.f, 0.f);
  for (int i = lo + part * 4 + wave; i < hi; i += 16) {
    float4 v = h4[(size_t)i * 64 + lane];
    acc.x += v.x; acc.y += v.y; acc.z += v.z; acc.w += v.w;
  }
  __shared__ float4 red[4][64];
  red[wave][lane] = acc;
  __syncthreads();
  if (wave == 0) {
    float4 a0 = red[0][lane], a1 = red[1][lane], a2 = red[2][lane], a3 = red[3][lane];
    float4 o;
    o.x = (a0.x + a1.x) + (a2.x + a3.x);
    o.y = (a0.y + a1.y) + (a2.y + a3.y);
    o.z = (a0.z + a1.z) + (a2.z + a3.z);
    o.w = (a0.w + a1.w) + (a2.w + a3.w);
    ((float4*)pws)[(size_t)(g * 4 + part) * 64 + lane] = o;
  }
  if (part == 0 && threadIdx.x == 0) cnts[g] = hi - lo;
}

// ---------------- combine partials + final linear [G,256]@[256,10] ----------------
__global__ void final_kernel(const float* __restrict__ pws, const int* __restrict__ cnts,
                             const float* __restrict__ Wf, const float* __restrict__ bf,
                             float* __restrict__ pooled_out, float* __restrict__ out) {
  int g = blockIdx.x, t = threadIdx.x;
  float s = pws[(size_t)(g * 4 + 0) * 256 + t] + pws[(size_t)(g * 4 + 1) * 256 + t] +
            pws[(size_t)(g * 4 + 2) * 256 + t] + pws[(size_t)(g * 4 + 3) * 256 + t];
  float inv = 1.0f / fmaxf((float)cnts[g], 1.0f);
  float pv = s * inv;
  pooled_out[g * HC + t] = pv;
  __shared__ float p[HC];
  p[t] = pv;
  __syncthreads();
  if (t < 10) {
    float acc = bf[t];
    for (int c = 0; c < HC; ++c) acc += p[c] * Wf[c * 10 + t];
    out[g * 10 + t] = acc;
  }
}

extern "C" void kernel_launch(void* const* d_in, const int* in_sizes, int n_in,
                              void* d_out, int out_size, void* d_ws, size_t ws_size,
                              hipStream_t stream) {
  const float* x    = (const float*)d_in[0];
  const int*   ei   = (const int*)d_in[1];
  const int*   batch = (const int*)d_in[3];
  const float* W1   = (const float*)d_in[4];
  const float* as1  = (const float*)d_in[5];
  const float* ad1  = (const float*)d_in[6];
  const float* b1   = (const float*)d_in[7];
  const float* W2   = (const float*)d_in[8];
  const float* as2  = (const float*)d_in[9];
  const float* ad2  = (const float*)d_in[10];
  const float* b2   = (const float*)d_in[11];
  const float* Wf   = (const float*)d_in[12];
  const float* bf   = (const float*)d_in[13];
  float* out = (float*)d_out;

  const int N = in_sizes[0] / HC;  // 50000
  const int E = in_sizes[1] / 2;   // 800000

  // workspace layout (256B-aligned chunks). bufB (fp32, N*HC) aliases xh+xl.
  char* base = (char*)d_ws;
  size_t off = 0;
  auto alloc = [&](size_t bytes) {
    char* p = base + off;
    off = (off + bytes + 255) & ~(size_t)255;
    return p;
  };
  ush* xh = (ush*)alloc((size_t)N * HC * 2);   // bf16 hi (aliased by bufB)
  ush* xl = (ush*)alloc((size_t)N * HC * 2);   // bf16 lo
  float* bufB = (float*)xh;                    // fp32 agg2 output (alias)
  ush* hbf = (ush*)alloc((size_t)N * HC * 2);  // bf16 projected features
  float* asrc = (float*)alloc((size_t)N * HEADS * 4);
  float* adst = (float*)alloc((size_t)N * HEADS * 4);
  int* counts = (int*)alloc((size_t)N * 4);
  int* row_ptr = (int*)alloc((size_t)(N + 1) * 4);
  int* cursor = (int*)alloc((size_t)N * 4);
  int* srcs = (int*)alloc((size_t)(E + N) * 4);
  int* bsums = (int*)alloc(((N + 1023) / 1024) * 4);
  ush* Bth = (ush*)alloc((size_t)HC * HC * 2);
  ush* Btl = (ush*)alloc((size_t)HC * HC * 2);
  float* pws = (float*)alloc((size_t)GG * 4 * HC * 4);
  int* cnts = (int*)alloc((size_t)GG * 4);

  int nb = (N + 1023) / 1024;

  // CSR build
  fill_counts_kernel<<<(N + 255) / 256, 256, 0, stream>>>(counts, N);
  hist_kernel<<<(E + 255) / 256, 256, 0, stream>>>(ei, counts, E);
  scan_pass1<<<nb, 256, 0, stream>>>(counts, bsums, N);
  scan_pass2<<<1, 256, 0, stream>>>(bsums, row_ptr, nb, N);
  scan_pass3<<<nb, 256, 0, stream>>>(counts, bsums, row_ptr, cursor, N);
  scatter_kernel<<<(E + N + 255) / 256, 256, 0, stream>>>(ei, cursor, srcs, E, N);

  dim3 ggrid(2, (N + 127) / 128);
  int agg_blocks = (N + 3) / 4;

  // split x into bf16 hi/lo once
  splitA_kernel<<<(N * HC / 4 + 255) / 256, 256, 0, stream>>>(x, xh, xl, N * HC);

  // layer 1 (aggregate emits bf16 hi/lo for layer-2 GEMM)
  convertB_kernel<<<HC, HC, 0, stream>>>(W1, Bth, Btl);
  gemm_kernel<<<ggrid, 256, 0, stream>>>(xh, xl, Bth, Btl, as1, ad1, hbf, asrc, adst, N);
  aggregate_kernel<<<agg_blocks, 256, 0, stream>>>(hbf, asrc, adst, row_ptr, srcs, b1,
                                                   nullptr, xh, xl, N);

  // layer 2 (aggregate emits fp32 for pooling)
  convertB_kernel<<<HC, HC, 0, stream>>>(W2, Bth, Btl);
  gemm_kernel<<<ggrid, 256, 0, stream>>>(xh, xl, Bth, Btl, as2, ad2, hbf, asrc, adst, N);
  aggregate_kernel<<<agg_blocks, 256, 0, stream>>>(hbf, asrc, adst, row_ptr, srcs, b2,
                                                   bufB, nullptr, nullptr, N);

  // pooling + classifier
  dim3 pgrid(GG, 4);
  pool_kernel<<<pgrid, 256, 0, stream>>>(bufB, batch, pws, cnts, N);
  final_kernel<<<GG, 256, 0, stream>>>(pws, cnts, Wf, bf, out + GG * 10, out);
}